// Round 1
// baseline (5597.786 us; speedup 1.0000x reference)
//
#include <hip/hip_runtime.h>
#include <math.h>

#define DIM    1024
#define HEADS  16
#define HDIM   64
#define HIDDEN 4096
#define BATCH  4
#define SEQ    1024
#define ROWS   (BATCH * SEQ)   // 4096

// ---------------- LayerNorm: one block (256 thr) per row of 1024 ----------------
__global__ __launch_bounds__(256) void ln_kernel(const float* __restrict__ x,
                                                 const float* __restrict__ g,
                                                 const float* __restrict__ b,
                                                 float* __restrict__ out) {
    int row = blockIdx.x;
    const float* xr = x + (size_t)row * DIM;
    float* orow = out + (size_t)row * DIM;
    int t = threadIdx.x;                       // 0..255, each owns 4 elems
    float4 v = *((const float4*)(xr + t * 4));
    float s  = v.x + v.y + v.z + v.w;
    float ss = v.x * v.x + v.y * v.y + v.z * v.z + v.w * v.w;
    __shared__ float red1[256], red2[256];
    red1[t] = s; red2[t] = ss;
    __syncthreads();
    for (int off = 128; off > 0; off >>= 1) {
        if (t < off) { red1[t] += red1[t + off]; red2[t] += red2[t + off]; }
        __syncthreads();
    }
    float mu   = red1[0] * (1.0f / DIM);
    float var  = red2[0] * (1.0f / DIM) - mu * mu;   // biased var, matches jnp.var
    float rstd = rsqrtf(var + 1e-5f);
    float4 gv = *((const float4*)(g + t * 4));
    float4 bv = *((const float4*)(b + t * 4));
    float4 o;
    o.x = (v.x - mu) * rstd * gv.x + bv.x;
    o.y = (v.y - mu) * rstd * gv.y + bv.y;
    o.z = (v.z - mu) * rstd * gv.z + bv.z;
    o.w = (v.w - mu) * rstd * gv.w + bv.w;
    *((float4*)(orow + t * 4)) = o;
}

// ---------------- Tiled fp32 GEMM: C = A[M,K] @ B[K,N] + bias, optional fuse ----
// fuse: 0 = none, 1 = exact GELU, 2 = + add[m,n] (residual)
__global__ __launch_bounds__(256) void gemm_kernel(const float* __restrict__ A,
                                                   const float* __restrict__ B,
                                                   const float* __restrict__ bias,
                                                   const float* __restrict__ add,
                                                   float* __restrict__ C,
                                                   int M, int N, int K, int fuse) {
    const int TK = 16;
    __shared__ float As[TK][68];   // [k][m]  stride 68 floats = 272 B (16B-aligned)
    __shared__ float Bs[TK][68];   // [k][n]
    int tid = threadIdx.x;
    int tx  = tid & 15;            // n direction
    int ty  = tid >> 4;            // m direction
    int m0 = blockIdx.y * 64, n0 = blockIdx.x * 64;
    float acc[4][4] = {{0.f}};

    for (int k0 = 0; k0 < K; k0 += TK) {
        // A tile: 64 (m) x 16 (k) -> As[k][m]
        #pragma unroll
        for (int l = 0; l < 4; ++l) {
            int idx = tid + l * 256;        // 0..1023
            int i = idx >> 4;               // m 0..63
            int j = idx & 15;               // k 0..15
            As[j][i] = A[(size_t)(m0 + i) * K + k0 + j];
        }
        // B tile: 16 (k) x 64 (n) -> Bs[k][n]
        #pragma unroll
        for (int l = 0; l < 4; ++l) {
            int idx = tid + l * 256;
            int j = idx >> 6;               // k 0..15
            int i = idx & 63;               // n 0..63
            Bs[j][i] = B[(size_t)(k0 + j) * N + n0 + i];
        }
        __syncthreads();
        #pragma unroll
        for (int kk = 0; kk < TK; ++kk) {
            float4 a4 = *((const float4*)&As[kk][ty * 4]);
            float4 b4 = *((const float4*)&Bs[kk][tx * 4]);
            float a[4] = {a4.x, a4.y, a4.z, a4.w};
            float b[4] = {b4.x, b4.y, b4.z, b4.w};
            #pragma unroll
            for (int u = 0; u < 4; ++u)
                #pragma unroll
                for (int v = 0; v < 4; ++v)
                    acc[u][v] += a[u] * b[v];
        }
        __syncthreads();
    }

    int nbase = n0 + tx * 4;
    float4 bi = *((const float4*)(bias + nbase));
    #pragma unroll
    for (int u = 0; u < 4; ++u) {
        int m = m0 + ty * 4 + u;
        float4 r;
        r.x = acc[u][0] + bi.x;
        r.y = acc[u][1] + bi.y;
        r.z = acc[u][2] + bi.z;
        r.w = acc[u][3] + bi.w;
        if (fuse == 1) {   // exact GELU: 0.5*x*(1+erf(x/sqrt(2)))
            r.x = 0.5f * r.x * (1.0f + erff(r.x * 0.70710678f));
            r.y = 0.5f * r.y * (1.0f + erff(r.y * 0.70710678f));
            r.z = 0.5f * r.z * (1.0f + erff(r.z * 0.70710678f));
            r.w = 0.5f * r.w * (1.0f + erff(r.w * 0.70710678f));
        } else if (fuse == 2) {
            float4 ad = *((const float4*)(add + (size_t)m * N + nbase));
            r.x += ad.x; r.y += ad.y; r.z += ad.z; r.w += ad.w;
        }
        *((float4*)(C + (size_t)m * N + nbase)) = r;
    }
}

// ---------------- Attention: one wave per (b,h,q); online softmax ----------------
// qkv layout: [B, N, 3, HEADS, HDIM]  (i.e., [B,N,3C] with C = HEADS*HDIM)
__global__ __launch_bounds__(64) void attn_kernel(const float* __restrict__ qkv,
                                                  float* __restrict__ out) {
    int idx = blockIdx.x;
    int q  = idx & (SEQ - 1);
    int bh = idx >> 10;            // SEQ = 1024
    int h  = bh & (HEADS - 1);
    int b  = bh >> 4;
    int d  = threadIdx.x;          // 0..63
    const float scale = 0.125f;    // HDIM^-0.5

    const float* base = qkv + (size_t)b * SEQ * 3 * DIM;
    float qv = base[(size_t)q * 3 * DIM + h * HDIM + d];

    float m = -1e30f, l = 0.f, o = 0.f;
    for (int k = 0; k < SEQ; ++k) {
        const float* kr = base + (size_t)k * 3 * DIM + DIM + h * HDIM;
        float kv = kr[d];
        float vv = kr[DIM + d];                    // V row at +DIM past K row
        float p = qv * kv;
        #pragma unroll
        for (int off = 32; off > 0; off >>= 1)
            p += __shfl_xor(p, off, 64);
        float s  = p * scale;
        float mn = fmaxf(m, s);
        float alpha = __expf(m - mn);
        float e     = __expf(s - mn);
        l = l * alpha + e;
        o = o * alpha + e * vv;
        m = mn;
    }
    out[((size_t)(b * SEQ + q)) * DIM + h * HDIM + d] = o / l;
}

extern "C" void kernel_launch(void* const* d_in, const int* in_sizes, int n_in,
                              void* d_out, int out_size, void* d_ws, size_t ws_size,
                              hipStream_t stream) {
    const float* x      = (const float*)d_in[0];
    const float* ln1_g  = (const float*)d_in[1];
    const float* ln1_b  = (const float*)d_in[2];
    const float* ln2_g  = (const float*)d_in[3];
    const float* ln2_b  = (const float*)d_in[4];
    const float* qkv_w  = (const float*)d_in[5];
    const float* qkv_b  = (const float*)d_in[6];
    const float* proj_w = (const float*)d_in[7];
    const float* proj_b = (const float*)d_in[8];
    const float* fc1_w  = (const float*)d_in[9];
    const float* fc1_b  = (const float*)d_in[10];
    const float* fc2_w  = (const float*)d_in[11];
    const float* fc2_b  = (const float*)d_in[12];
    float* out = (float*)d_out;

    // workspace: bufA = 4M floats (LN out / attn out), bufB = 16M floats (qkv / gelu)
    float* bufA = (float*)d_ws;
    float* bufB = bufA + (size_t)ROWS * DIM;

    // 1) h1 = LN1(x)
    ln_kernel<<<ROWS, 256, 0, stream>>>(x, ln1_g, ln1_b, bufA);
    // 2) qkv = h1 @ qkv_w + qkv_b            [4096 x 3072]
    gemm_kernel<<<dim3(3 * DIM / 64, ROWS / 64), 256, 0, stream>>>(
        bufA, qkv_w, qkv_b, nullptr, bufB, ROWS, 3 * DIM, DIM, 0);
    // 3) o = attention(qkv)                  [4096 x 1024]
    attn_kernel<<<BATCH * HEADS * SEQ, 64, 0, stream>>>(bufB, bufA);
    // 4) x1 = x + o @ proj_w + proj_b  -> d_out
    gemm_kernel<<<dim3(DIM / 64, ROWS / 64), 256, 0, stream>>>(
        bufA, proj_w, proj_b, x, out, ROWS, DIM, DIM, 2);
    // 5) h2 = LN2(x1)
    ln_kernel<<<ROWS, 256, 0, stream>>>(out, ln2_g, ln2_b, bufA);
    // 6) g = gelu(h2 @ fc1_w + fc1_b)        [4096 x 4096]
    gemm_kernel<<<dim3(HIDDEN / 64, ROWS / 64), 256, 0, stream>>>(
        bufA, fc1_w, fc1_b, nullptr, bufB, ROWS, HIDDEN, DIM, 1);
    // 7) out = x1 + g @ fc2_w + fc2_b        (in-place residual on d_out)
    gemm_kernel<<<dim3(DIM / 64, ROWS / 64), 256, 0, stream>>>(
        bufB, fc2_w, fc2_b, out, out, ROWS, DIM, HIDDEN, 2);
}

// Round 2
// 1777.020 us; speedup vs baseline: 3.1501x; 3.1501x over previous
//
#include <hip/hip_runtime.h>
#include <math.h>

#define DIM    1024
#define HEADS  16
#define HDIM   64
#define HIDDEN 4096
#define BATCH  4
#define SEQ    1024
#define ROWS   (BATCH * SEQ)   // 4096

// ---------------- LayerNorm: one block (256 thr) per row of 1024 ----------------
__global__ __launch_bounds__(256) void ln_kernel(const float* __restrict__ x,
                                                 const float* __restrict__ g,
                                                 const float* __restrict__ b,
                                                 float* __restrict__ out) {
    int row = blockIdx.x;
    const float* xr = x + (size_t)row * DIM;
    float* orow = out + (size_t)row * DIM;
    int t = threadIdx.x;                       // 0..255, each owns 4 elems
    float4 v = *((const float4*)(xr + t * 4));
    float s  = v.x + v.y + v.z + v.w;
    float ss = v.x * v.x + v.y * v.y + v.z * v.z + v.w * v.w;
    __shared__ float red1[256], red2[256];
    red1[t] = s; red2[t] = ss;
    __syncthreads();
    for (int off = 128; off > 0; off >>= 1) {
        if (t < off) { red1[t] += red1[t + off]; red2[t] += red2[t + off]; }
        __syncthreads();
    }
    float mu   = red1[0] * (1.0f / DIM);
    float var  = red2[0] * (1.0f / DIM) - mu * mu;   // biased var, matches jnp.var
    float rstd = rsqrtf(var + 1e-5f);
    float4 gv = *((const float4*)(g + t * 4));
    float4 bv = *((const float4*)(b + t * 4));
    float4 o;
    o.x = (v.x - mu) * rstd * gv.x + bv.x;
    o.y = (v.y - mu) * rstd * gv.y + bv.y;
    o.z = (v.z - mu) * rstd * gv.z + bv.z;
    o.w = (v.w - mu) * rstd * gv.w + bv.w;
    *((float4*)(orow + t * 4)) = o;
}

// ---------------- Tiled fp32 GEMM: C = A[M,K] @ B[K,N] + bias, optional fuse ----
// fuse: 0 = none, 1 = exact GELU, 2 = + add[m,n] (residual)
__global__ __launch_bounds__(256) void gemm_kernel(const float* __restrict__ A,
                                                   const float* __restrict__ B,
                                                   const float* __restrict__ bias,
                                                   const float* __restrict__ add,
                                                   float* __restrict__ C,
                                                   int M, int N, int K, int fuse) {
    const int TK = 16;
    __shared__ float As[TK][68];   // [k][m]  stride 68 floats = 272 B (16B-aligned)
    __shared__ float Bs[TK][68];   // [k][n]
    int tid = threadIdx.x;
    int tx  = tid & 15;            // n direction
    int ty  = tid >> 4;            // m direction
    int m0 = blockIdx.y * 64, n0 = blockIdx.x * 64;
    float acc[4][4] = {{0.f}};

    for (int k0 = 0; k0 < K; k0 += TK) {
        // A tile: 64 (m) x 16 (k) -> As[k][m]
        #pragma unroll
        for (int l = 0; l < 4; ++l) {
            int idx = tid + l * 256;        // 0..1023
            int i = idx >> 4;               // m 0..63
            int j = idx & 15;               // k 0..15
            As[j][i] = A[(size_t)(m0 + i) * K + k0 + j];
        }
        // B tile: 16 (k) x 64 (n) -> Bs[k][n]
        #pragma unroll
        for (int l = 0; l < 4; ++l) {
            int idx = tid + l * 256;
            int j = idx >> 6;               // k 0..15
            int i = idx & 63;               // n 0..63
            Bs[j][i] = B[(size_t)(k0 + j) * N + n0 + i];
        }
        __syncthreads();
        #pragma unroll
        for (int kk = 0; kk < TK; ++kk) {
            float4 a4 = *((const float4*)&As[kk][ty * 4]);
            float4 b4 = *((const float4*)&Bs[kk][tx * 4]);
            float a[4] = {a4.x, a4.y, a4.z, a4.w};
            float b[4] = {b4.x, b4.y, b4.z, b4.w};
            #pragma unroll
            for (int u = 0; u < 4; ++u)
                #pragma unroll
                for (int v = 0; v < 4; ++v)
                    acc[u][v] += a[u] * b[v];
        }
        __syncthreads();
    }

    int nbase = n0 + tx * 4;
    float4 bi = *((const float4*)(bias + nbase));
    #pragma unroll
    for (int u = 0; u < 4; ++u) {
        int m = m0 + ty * 4 + u;
        float4 r;
        r.x = acc[u][0] + bi.x;
        r.y = acc[u][1] + bi.y;
        r.z = acc[u][2] + bi.z;
        r.w = acc[u][3] + bi.w;
        if (fuse == 1) {   // exact GELU: 0.5*x*(1+erf(x/sqrt(2)))
            r.x = 0.5f * r.x * (1.0f + erff(r.x * 0.70710678f));
            r.y = 0.5f * r.y * (1.0f + erff(r.y * 0.70710678f));
            r.z = 0.5f * r.z * (1.0f + erff(r.z * 0.70710678f));
            r.w = 0.5f * r.w * (1.0f + erff(r.w * 0.70710678f));
        } else if (fuse == 2) {
            float4 ad = *((const float4*)(add + (size_t)m * N + nbase));
            r.x += ad.x; r.y += ad.y; r.z += ad.z; r.w += ad.w;
        }
        *((float4*)(C + (size_t)m * N + nbase)) = r;
    }
}

// ------------- Flash attention: block = (b,h) x 64-q tile, 256 threads ----------
// qkv layout: [B, N, 3, HEADS, HDIM]. Online softmax over 64-k tiles.
// Per thread: 4x4 micro-tile of S (q x k) and of O (q x d).
__global__ __launch_bounds__(256) void fattn_kernel(const float* __restrict__ qkv,
                                                    float* __restrict__ out) {
    __shared__ float Qs[64][68];    // [d][q], prescaled by 0.125
    __shared__ float KPs[64][68];   // K^T as [d][k], reused as P [k][q]
    __shared__ float Vs[64][68];    // [k][d]

    int bh = blockIdx.y;
    int h  = bh & (HEADS - 1);
    int b  = bh >> 4;
    int q0 = blockIdx.x * 64;
    int tid = threadIdx.x;
    int tx = tid & 15;              // k (then d) direction
    int ty = tid >> 4;              // q direction
    const float* base = qkv + (size_t)b * SEQ * 3 * DIM;

    // Load Q tile transposed: Qs[d][q] = Q[q0+q][d] * scale
    {
        int i = tid >> 2;           // row 0..63
        int c = (tid & 3) * 4;
        #pragma unroll
        for (int p = 0; p < 4; ++p) {
            int d0 = c + p * 16;
            float4 v = *((const float4*)(base + (size_t)(q0 + i) * 3 * DIM + h * HDIM + d0));
            Qs[d0 + 0][i] = v.x * 0.125f;
            Qs[d0 + 1][i] = v.y * 0.125f;
            Qs[d0 + 2][i] = v.z * 0.125f;
            Qs[d0 + 3][i] = v.w * 0.125f;
        }
    }

    float m[4], l[4], acc_o[4][4];
    #pragma unroll
    for (int u = 0; u < 4; ++u) {
        m[u] = -1e30f; l[u] = 0.f;
        #pragma unroll
        for (int v = 0; v < 4; ++v) acc_o[u][v] = 0.f;
    }

    for (int k0 = 0; k0 < SEQ; k0 += 64) {
        // Load K tile transposed (KPs[d][k]) and V tile direct (Vs[k][d])
        {
            int i = tid >> 2;
            int c = (tid & 3) * 4;
            const float* kr = base + (size_t)(k0 + i) * 3 * DIM + DIM + h * HDIM;
            #pragma unroll
            for (int p = 0; p < 4; ++p) {
                int d0 = c + p * 16;
                float4 kv = *((const float4*)(kr + d0));
                KPs[d0 + 0][i] = kv.x;
                KPs[d0 + 1][i] = kv.y;
                KPs[d0 + 2][i] = kv.z;
                KPs[d0 + 3][i] = kv.w;
                *((float4*)&Vs[i][d0]) = *((const float4*)(kr + DIM + d0));
            }
        }
        __syncthreads();

        // S = Q K^T  (pre-scaled), 4x4 per thread
        float s[4][4] = {{0.f}};
        #pragma unroll 8
        for (int d = 0; d < 64; ++d) {
            float4 a4 = *((const float4*)&Qs[d][ty * 4]);
            float4 b4 = *((const float4*)&KPs[d][tx * 4]);
            float a[4] = {a4.x, a4.y, a4.z, a4.w};
            float bb[4] = {b4.x, b4.y, b4.z, b4.w};
            #pragma unroll
            for (int u = 0; u < 4; ++u)
                #pragma unroll
                for (int v = 0; v < 4; ++v)
                    s[u][v] += a[u] * bb[v];
        }

        // Online softmax update (row stats across the 16 tx threads)
        float p[4][4];
        #pragma unroll
        for (int u = 0; u < 4; ++u) {
            float rm = fmaxf(fmaxf(s[u][0], s[u][1]), fmaxf(s[u][2], s[u][3]));
            #pragma unroll
            for (int off = 1; off < 16; off <<= 1)
                rm = fmaxf(rm, __shfl_xor(rm, off, 64));
            float mn = fmaxf(m[u], rm);
            float alpha = __expf(m[u] - mn);
            m[u] = mn;
            float rs = 0.f;
            #pragma unroll
            for (int v = 0; v < 4; ++v) {
                p[u][v] = __expf(s[u][v] - mn);
                rs += p[u][v];
            }
            #pragma unroll
            for (int off = 1; off < 16; off <<= 1)
                rs += __shfl_xor(rs, off, 64);
            l[u] = l[u] * alpha + rs;
            #pragma unroll
            for (int v = 0; v < 4; ++v) acc_o[u][v] *= alpha;
        }

        __syncthreads();   // everyone done reading K from KPs
        // Write P into KPs as [k][q]
        #pragma unroll
        for (int u = 0; u < 4; ++u)
            #pragma unroll
            for (int v = 0; v < 4; ++v)
                KPs[tx * 4 + v][ty * 4 + u] = p[u][v];
        __syncthreads();

        // O += P V, 4x4 per thread (q x d)
        #pragma unroll 8
        for (int k = 0; k < 64; ++k) {
            float4 p4 = *((const float4*)&KPs[k][ty * 4]);
            float4 v4 = *((const float4*)&Vs[k][tx * 4]);
            float pp[4] = {p4.x, p4.y, p4.z, p4.w};
            float vv[4] = {v4.x, v4.y, v4.z, v4.w};
            #pragma unroll
            for (int u = 0; u < 4; ++u)
                #pragma unroll
                for (int v = 0; v < 4; ++v)
                    acc_o[u][v] += pp[u] * vv[v];
        }
        __syncthreads();   // before next tile overwrites KPs/Vs
    }

    // Epilogue: divide by l, write [B,N,C]
    #pragma unroll
    for (int u = 0; u < 4; ++u) {
        float inv = 1.0f / l[u];
        float4 r;
        r.x = acc_o[u][0] * inv;
        r.y = acc_o[u][1] * inv;
        r.z = acc_o[u][2] * inv;
        r.w = acc_o[u][3] * inv;
        size_t row = (size_t)(b * SEQ + q0 + ty * 4 + u);
        *((float4*)(out + row * DIM + h * HDIM + tx * 4)) = r;
    }
}

extern "C" void kernel_launch(void* const* d_in, const int* in_sizes, int n_in,
                              void* d_out, int out_size, void* d_ws, size_t ws_size,
                              hipStream_t stream) {
    const float* x      = (const float*)d_in[0];
    const float* ln1_g  = (const float*)d_in[1];
    const float* ln1_b  = (const float*)d_in[2];
    const float* ln2_g  = (const float*)d_in[3];
    const float* ln2_b  = (const float*)d_in[4];
    const float* qkv_w  = (const float*)d_in[5];
    const float* qkv_b  = (const float*)d_in[6];
    const float* proj_w = (const float*)d_in[7];
    const float* proj_b = (const float*)d_in[8];
    const float* fc1_w  = (const float*)d_in[9];
    const float* fc1_b  = (const float*)d_in[10];
    const float* fc2_w  = (const float*)d_in[11];
    const float* fc2_b  = (const float*)d_in[12];
    float* out = (float*)d_out;

    // workspace: bufA = 4M floats (LN out / attn out), bufB = 16M floats (qkv / gelu)
    float* bufA = (float*)d_ws;
    float* bufB = bufA + (size_t)ROWS * DIM;

    // 1) h1 = LN1(x)
    ln_kernel<<<ROWS, 256, 0, stream>>>(x, ln1_g, ln1_b, bufA);
    // 2) qkv = h1 @ qkv_w + qkv_b            [4096 x 3072]
    gemm_kernel<<<dim3(3 * DIM / 64, ROWS / 64), 256, 0, stream>>>(
        bufA, qkv_w, qkv_b, nullptr, bufB, ROWS, 3 * DIM, DIM, 0);
    // 3) o = flash_attention(qkv)            [4096 x 1024]
    fattn_kernel<<<dim3(SEQ / 64, BATCH * HEADS), 256, 0, stream>>>(bufB, bufA);
    // 4) x1 = x + o @ proj_w + proj_b  -> d_out
    gemm_kernel<<<dim3(DIM / 64, ROWS / 64), 256, 0, stream>>>(
        bufA, proj_w, proj_b, x, out, ROWS, DIM, DIM, 2);
    // 5) h2 = LN2(x1)
    ln_kernel<<<ROWS, 256, 0, stream>>>(out, ln2_g, ln2_b, bufA);
    // 6) g = gelu(h2 @ fc1_w + fc1_b)        [4096 x 4096]
    gemm_kernel<<<dim3(HIDDEN / 64, ROWS / 64), 256, 0, stream>>>(
        bufA, fc1_w, fc1_b, nullptr, bufB, ROWS, HIDDEN, DIM, 1);
    // 7) out = x1 + g @ fc2_w + fc2_b        (in-place residual on d_out)
    gemm_kernel<<<dim3(DIM / 64, ROWS / 64), 256, 0, stream>>>(
        bufB, fc2_w, fc2_b, out, out, ROWS, DIM, HIDDEN, 2);
}

// Round 3
// 699.128 us; speedup vs baseline: 8.0068x; 2.5418x over previous
//
#include <hip/hip_runtime.h>
#include <math.h>

#define DIM    1024
#define HEADS  16
#define HDIM   64
#define HIDDEN 4096
#define BATCH  4
#define SEQ    1024
#define ROWS   (BATCH * SEQ)   // 4096

typedef short s16x8 __attribute__((ext_vector_type(8)));
typedef float f32x4 __attribute__((ext_vector_type(4)));

// ---- bf16 helpers (manual, bit-exact, no __hip_bfloat16 API dependence) ----
__device__ __forceinline__ float blo(unsigned int u) {
    union { unsigned int i; float f; } x; x.i = u << 16; return x.f;
}
__device__ __forceinline__ float bhi(unsigned int u) {
    union { unsigned int i; float f; } x; x.i = u & 0xffff0000u; return x.f;
}
__device__ __forceinline__ unsigned short f2b(float f) {   // round-to-nearest-even
    union { float f; unsigned int i; } x; x.f = f;
    unsigned int r = x.i + 0x7fffu + ((x.i >> 16) & 1u);
    return (unsigned short)(r >> 16);
}

// ---- async global->LDS, 16B per lane, wave-uniform LDS base + lane*16 ----
__device__ __forceinline__ void gload_lds16(const void* g, void* l) {
    __builtin_amdgcn_global_load_lds(
        (const __attribute__((address_space(1))) unsigned int*)g,
        (__attribute__((address_space(3))) unsigned int*)l, 16, 0, 0);
}

// ---------------- LayerNorm: one block per row; fp32 in -> bf16 out ----------------
__global__ __launch_bounds__(256) void ln_kernel(const float* __restrict__ x,
                                                 const float* __restrict__ g,
                                                 const float* __restrict__ b,
                                                 unsigned short* __restrict__ out) {
    int row = blockIdx.x;
    const float* xr = x + (size_t)row * DIM;
    unsigned short* orow = out + (size_t)row * DIM;
    int t = threadIdx.x;
    float4 v = *((const float4*)(xr + t * 4));
    float s  = v.x + v.y + v.z + v.w;
    float ss = v.x * v.x + v.y * v.y + v.z * v.z + v.w * v.w;
    __shared__ float red1[256], red2[256];
    red1[t] = s; red2[t] = ss;
    __syncthreads();
    for (int off = 128; off > 0; off >>= 1) {
        if (t < off) { red1[t] += red1[t + off]; red2[t] += red2[t + off]; }
        __syncthreads();
    }
    float mu   = red1[0] * (1.0f / DIM);
    float var  = red2[0] * (1.0f / DIM) - mu * mu;
    float rstd = rsqrtf(var + 1e-5f);
    float4 gv = *((const float4*)(g + t * 4));
    float4 bv = *((const float4*)(b + t * 4));
    ushort4 o;
    o.x = f2b((v.x - mu) * rstd * gv.x + bv.x);
    o.y = f2b((v.y - mu) * rstd * gv.y + bv.y);
    o.z = f2b((v.z - mu) * rstd * gv.z + bv.z);
    o.w = f2b((v.w - mu) * rstd * gv.w + bv.w);
    *((ushort4*)(orow + t * 4)) = o;
}

// ------------- Weight convert+transpose: W fp32 [K,N] -> Wt bf16 [N,K] -------------
__global__ __launch_bounds__(256) void wconv_t(const float* __restrict__ W,
                                               unsigned short* __restrict__ Wt,
                                               int K, int N) {
    __shared__ unsigned short T[64][68];   // [n][k] within tile
    int t = threadIdx.x;
    int n0 = blockIdx.x * 64, k0 = blockIdx.y * 64;
    int cr = t >> 4;            // 0..15 row stepper
    int cc = (t & 15) * 4;      // col group
    #pragma unroll
    for (int r = 0; r < 4; ++r) {
        int kk = cr + 16 * r;
        float4 v = *((const float4*)(W + (size_t)(k0 + kk) * N + n0 + cc));
        T[cc + 0][kk] = f2b(v.x);
        T[cc + 1][kk] = f2b(v.y);
        T[cc + 2][kk] = f2b(v.z);
        T[cc + 3][kk] = f2b(v.w);
    }
    __syncthreads();
    #pragma unroll
    for (int r = 0; r < 4; ++r) {
        int nn = cr + 16 * r;
        *((ushort4*)(Wt + (size_t)(n0 + nn) * K + k0 + cc)) = *((ushort4*)&T[nn][cc]);
    }
}

// ---------------- MFMA GEMM: C = A[M,K](bf16) @ Bt[N,K]^T(bf16) + bias ----------------
// fuse: 0 = bias, bf16 out; 1 = bias+exact GELU, bf16 out; 2 = bias+residual(fp32), fp32 out
// 128x128 tile, BK=64, 4 waves (2x2), each wave 4x4 of mfma_f32_16x16x32_bf16.
// LDS holds tiles in FRAGMENT ORDER: chunk cid = mb*2+kc (16 rows x 32 k), 1024B each,
// lane L's 16B at cid*1024 + L*16 = A[m0+mb*16+(L&15)][k0+kc*32+(L>>4)*8 .. +7].
__global__ __launch_bounds__(256) void mfma_gemm(const unsigned short* __restrict__ A,
                                                 const unsigned short* __restrict__ Bt,
                                                 const float* __restrict__ bias,
                                                 const float* __restrict__ add,
                                                 void* __restrict__ Cout,
                                                 int M, int N, int K, int fuse) {
    __shared__ short Asm[8192];   // 16 chunks * 512 bf16 = 16 KB
    __shared__ short Bsm[8192];

    const int tid  = threadIdx.x;
    const int lane = tid & 63;
    const int wave = tid >> 6;          // 0..3
    const int wy = wave >> 1, wx = wave & 1;
    const int lr = lane & 15;
    const int lq = lane >> 4;
    const int m0 = blockIdx.y * 128, n0 = blockIdx.x * 128;

    f32x4 acc[4][4];
    #pragma unroll
    for (int i = 0; i < 4; ++i)
        #pragma unroll
        for (int j = 0; j < 4; ++j)
            acc[i][j] = (f32x4){0.f, 0.f, 0.f, 0.f};

    // per-wave staging assignments (4 A-chunks + 4 B-chunks each)
    const unsigned short* ag[4]; const unsigned short* bg[4];
    short* al[4]; short* bl[4];
    #pragma unroll
    for (int j = 0; j < 4; ++j) {
        int cid = wave * 4 + j;
        int rb  = (cid >> 1) * 16 + lr;
        int kk  = (cid & 1) * 32 + lq * 8;
        ag[j] = A  + (size_t)(m0 + rb) * K + kk;
        bg[j] = Bt + (size_t)(n0 + rb) * K + kk;
        al[j] = &Asm[cid * 512];
        bl[j] = &Bsm[cid * 512];
    }

    for (int k0 = 0; k0 < K; k0 += 64) {
        #pragma unroll
        for (int j = 0; j < 4; ++j) {
            gload_lds16(ag[j], al[j]);
            gload_lds16(bg[j], bl[j]);
            ag[j] += 64; bg[j] += 64;
        }
        __syncthreads();
        #pragma unroll
        for (int kc = 0; kc < 2; ++kc) {
            s16x8 af[4], bf[4];
            #pragma unroll
            for (int i = 0; i < 4; ++i)
                af[i] = *((const s16x8*)&Asm[((wy * 4 + i) * 2 + kc) * 512 + lane * 8]);
            #pragma unroll
            for (int j = 0; j < 4; ++j)
                bf[j] = *((const s16x8*)&Bsm[((wx * 4 + j) * 2 + kc) * 512 + lane * 8]);
            #pragma unroll
            for (int i = 0; i < 4; ++i)
                #pragma unroll
                for (int j = 0; j < 4; ++j)
                    acc[i][j] = __builtin_amdgcn_mfma_f32_16x16x32_bf16(af[i], bf[j], acc[i][j], 0, 0, 0);
        }
        __syncthreads();
    }

    // Epilogue. C/D layout: col = lane&15, row = (lane>>4)*4 + reg.
    #pragma unroll
    for (int j = 0; j < 4; ++j) {
        int col = n0 + wx * 64 + j * 16 + lr;
        float bi = bias[col];
        #pragma unroll
        for (int i = 0; i < 4; ++i) {
            int row0 = m0 + wy * 64 + i * 16 + lq * 4;
            #pragma unroll
            for (int r = 0; r < 4; ++r) {
                float val = acc[i][j][r] + bi;
                size_t idx = (size_t)(row0 + r) * N + col;
                if (fuse == 2) {
                    ((float*)Cout)[idx] = val + add[idx];
                } else {
                    if (fuse == 1)
                        val = 0.5f * val * (1.0f + erff(val * 0.70710678f));
                    ((unsigned short*)Cout)[idx] = f2b(val);
                }
            }
        }
    }
}

// ------------- Flash attention: block = (b,h) x 64-q tile, 256 threads ----------
// qkv (bf16) layout: [B, N, 3, HEADS, HDIM]. fp32 compute, bf16 out.
__global__ __launch_bounds__(256) void fattn_kernel(const unsigned short* __restrict__ qkv,
                                                    unsigned short* __restrict__ out) {
    __shared__ float Qs[64][68];    // [d][q], prescaled by 0.125
    __shared__ float KPs[64][68];   // K^T as [d][k], reused as P [k][q]
    __shared__ float Vs[64][68];    // [k][d]

    int bh = blockIdx.y;
    int h  = bh & (HEADS - 1);
    int b  = bh >> 4;
    int q0 = blockIdx.x * 64;
    int tid = threadIdx.x;
    int tx = tid & 15;
    int ty = tid >> 4;
    const unsigned short* base = qkv + (size_t)b * SEQ * 3 * DIM;

    // Load Q tile transposed: Qs[d][q] = Q[q0+q][d] * scale
    {
        int i  = tid >> 2;
        int c0 = (tid & 3) * 16;
        const unsigned short* qr = base + (size_t)(q0 + i) * 3 * DIM + h * HDIM;
        #pragma unroll
        for (int p = 0; p < 2; ++p) {
            int d0 = c0 + p * 8;
            uint4 w = *((const uint4*)(qr + d0));
            Qs[d0 + 0][i] = blo(w.x) * 0.125f; Qs[d0 + 1][i] = bhi(w.x) * 0.125f;
            Qs[d0 + 2][i] = blo(w.y) * 0.125f; Qs[d0 + 3][i] = bhi(w.y) * 0.125f;
            Qs[d0 + 4][i] = blo(w.z) * 0.125f; Qs[d0 + 5][i] = bhi(w.z) * 0.125f;
            Qs[d0 + 6][i] = blo(w.w) * 0.125f; Qs[d0 + 7][i] = bhi(w.w) * 0.125f;
        }
    }

    float m[4], l[4], acc_o[4][4];
    #pragma unroll
    for (int u = 0; u < 4; ++u) {
        m[u] = -1e30f; l[u] = 0.f;
        #pragma unroll
        for (int v = 0; v < 4; ++v) acc_o[u][v] = 0.f;
    }

    for (int k0 = 0; k0 < SEQ; k0 += 64) {
        {
            int i  = tid >> 2;
            int c0 = (tid & 3) * 16;
            const unsigned short* kr = base + (size_t)(k0 + i) * 3 * DIM + DIM + h * HDIM;
            #pragma unroll
            for (int p = 0; p < 2; ++p) {
                int d0 = c0 + p * 8;
                uint4 kw = *((const uint4*)(kr + d0));
                KPs[d0 + 0][i] = blo(kw.x); KPs[d0 + 1][i] = bhi(kw.x);
                KPs[d0 + 2][i] = blo(kw.y); KPs[d0 + 3][i] = bhi(kw.y);
                KPs[d0 + 4][i] = blo(kw.z); KPs[d0 + 5][i] = bhi(kw.z);
                KPs[d0 + 6][i] = blo(kw.w); KPs[d0 + 7][i] = bhi(kw.w);
                uint4 vw = *((const uint4*)(kr + DIM + d0));
                *((float4*)&Vs[i][d0])     = make_float4(blo(vw.x), bhi(vw.x), blo(vw.y), bhi(vw.y));
                *((float4*)&Vs[i][d0 + 4]) = make_float4(blo(vw.z), bhi(vw.z), blo(vw.w), bhi(vw.w));
            }
        }
        __syncthreads();

        float s[4][4] = {{0.f}};
        #pragma unroll 8
        for (int d = 0; d < 64; ++d) {
            float4 a4 = *((const float4*)&Qs[d][ty * 4]);
            float4 b4 = *((const float4*)&KPs[d][tx * 4]);
            float a[4] = {a4.x, a4.y, a4.z, a4.w};
            float bb[4] = {b4.x, b4.y, b4.z, b4.w};
            #pragma unroll
            for (int u = 0; u < 4; ++u)
                #pragma unroll
                for (int v = 0; v < 4; ++v)
                    s[u][v] += a[u] * bb[v];
        }

        float p[4][4];
        #pragma unroll
        for (int u = 0; u < 4; ++u) {
            float rm = fmaxf(fmaxf(s[u][0], s[u][1]), fmaxf(s[u][2], s[u][3]));
            #pragma unroll
            for (int off = 1; off < 16; off <<= 1)
                rm = fmaxf(rm, __shfl_xor(rm, off, 64));
            float mn = fmaxf(m[u], rm);
            float alpha = __expf(m[u] - mn);
            m[u] = mn;
            float rs = 0.f;
            #pragma unroll
            for (int v = 0; v < 4; ++v) {
                p[u][v] = __expf(s[u][v] - mn);
                rs += p[u][v];
            }
            #pragma unroll
            for (int off = 1; off < 16; off <<= 1)
                rs += __shfl_xor(rs, off, 64);
            l[u] = l[u] * alpha + rs;
            #pragma unroll
            for (int v = 0; v < 4; ++v) acc_o[u][v] *= alpha;
        }

        __syncthreads();
        #pragma unroll
        for (int u = 0; u < 4; ++u)
            #pragma unroll
            for (int v = 0; v < 4; ++v)
                KPs[tx * 4 + v][ty * 4 + u] = p[u][v];
        __syncthreads();

        #pragma unroll 8
        for (int k = 0; k < 64; ++k) {
            float4 p4 = *((const float4*)&KPs[k][ty * 4]);
            float4 v4 = *((const float4*)&Vs[k][tx * 4]);
            float pp[4] = {p4.x, p4.y, p4.z, p4.w};
            float vv[4] = {v4.x, v4.y, v4.z, v4.w};
            #pragma unroll
            for (int u = 0; u < 4; ++u)
                #pragma unroll
                for (int v = 0; v < 4; ++v)
                    acc_o[u][v] += pp[u] * vv[v];
        }
        __syncthreads();
    }

    #pragma unroll
    for (int u = 0; u < 4; ++u) {
        float inv = 1.0f / l[u];
        ushort4 r;
        r.x = f2b(acc_o[u][0] * inv);
        r.y = f2b(acc_o[u][1] * inv);
        r.z = f2b(acc_o[u][2] * inv);
        r.w = f2b(acc_o[u][3] * inv);
        size_t row = (size_t)(b * SEQ + q0 + ty * 4 + u);
        *((ushort4*)(out + row * DIM + h * HDIM + tx * 4)) = r;
    }
}

extern "C" void kernel_launch(void* const* d_in, const int* in_sizes, int n_in,
                              void* d_out, int out_size, void* d_ws, size_t ws_size,
                              hipStream_t stream) {
    const float* x      = (const float*)d_in[0];
    const float* ln1_g  = (const float*)d_in[1];
    const float* ln1_b  = (const float*)d_in[2];
    const float* ln2_g  = (const float*)d_in[3];
    const float* ln2_b  = (const float*)d_in[4];
    const float* qkv_w  = (const float*)d_in[5];
    const float* qkv_b  = (const float*)d_in[6];
    const float* proj_w = (const float*)d_in[7];
    const float* proj_b = (const float*)d_in[8];
    const float* fc1_w  = (const float*)d_in[9];
    const float* fc1_b  = (const float*)d_in[10];
    const float* fc2_w  = (const float*)d_in[11];
    const float* fc2_b  = (const float*)d_in[12];
    float* out = (float*)d_out;

    // workspace layout (bytes)
    char* ws = (char*)d_ws;
    unsigned short* wT_qkv  = (unsigned short*)(ws);                          //  6 MB
    unsigned short* wT_proj = (unsigned short*)(ws + 6291456);                //  2 MB
    unsigned short* wT_fc1  = (unsigned short*)(ws + 6291456 + 2097152);      //  8 MB
    unsigned short* wT_fc2  = (unsigned short*)(ws + 6291456 + 2097152 + 8388608);  // 8 MB
    unsigned short* lnout   = (unsigned short*)(ws + 25165824);               //  8 MB
    unsigned short* attnout = (unsigned short*)(ws + 25165824 + 8388608);     //  8 MB
    unsigned short* bigbuf  = (unsigned short*)(ws + 25165824 + 16777216);    // 32 MB (qkv / gelu)

    // 0) weight convert+transpose to bf16 [N,K]
    wconv_t<<<dim3(3 * DIM / 64, DIM / 64), 256, 0, stream>>>(qkv_w, wT_qkv, DIM, 3 * DIM);
    wconv_t<<<dim3(DIM / 64, DIM / 64), 256, 0, stream>>>(proj_w, wT_proj, DIM, DIM);
    wconv_t<<<dim3(HIDDEN / 64, DIM / 64), 256, 0, stream>>>(fc1_w, wT_fc1, DIM, HIDDEN);
    wconv_t<<<dim3(DIM / 64, HIDDEN / 64), 256, 0, stream>>>(fc2_w, wT_fc2, HIDDEN, DIM);

    // 1) h1 = LN1(x) -> bf16
    ln_kernel<<<ROWS, 256, 0, stream>>>(x, ln1_g, ln1_b, lnout);
    // 2) qkv = h1 @ qkv_w + qkv_b -> bf16   [4096 x 3072]
    mfma_gemm<<<dim3(3 * DIM / 128, ROWS / 128), 256, 0, stream>>>(
        lnout, wT_qkv, qkv_b, nullptr, bigbuf, ROWS, 3 * DIM, DIM, 0);
    // 3) o = flash_attention(qkv) -> bf16   [4096 x 1024]
    fattn_kernel<<<dim3(SEQ / 64, BATCH * HEADS), 256, 0, stream>>>(bigbuf, attnout);
    // 4) x1 = x + o @ proj_w + proj_b -> d_out (fp32)
    mfma_gemm<<<dim3(DIM / 128, ROWS / 128), 256, 0, stream>>>(
        attnout, wT_proj, proj_b, x, out, ROWS, DIM, DIM, 2);
    // 5) h2 = LN2(x1) -> bf16
    ln_kernel<<<ROWS, 256, 0, stream>>>(out, ln2_g, ln2_b, lnout);
    // 6) g = gelu(h2 @ fc1_w + fc1_b) -> bf16  [4096 x 4096]
    mfma_gemm<<<dim3(HIDDEN / 128, ROWS / 128), 256, 0, stream>>>(
        lnout, wT_fc1, fc1_b, nullptr, bigbuf, ROWS, HIDDEN, DIM, 1);
    // 7) out = x1 + g @ fc2_w + fc2_b -> d_out (fp32)
    mfma_gemm<<<dim3(DIM / 128, ROWS / 128), 256, 0, stream>>>(
        bigbuf, wT_fc2, fc2_b, out, out, ROWS, DIM, HIDDEN, 2);
}

// Round 4
// 531.873 us; speedup vs baseline: 10.5247x; 1.3145x over previous
//
#include <hip/hip_runtime.h>
#include <math.h>

#define DIM    1024
#define HEADS  16
#define HDIM   64
#define HIDDEN 4096
#define BATCH  4
#define SEQ    1024
#define ROWS   (BATCH * SEQ)   // 4096

typedef short s16x8 __attribute__((ext_vector_type(8)));
typedef float f32x4 __attribute__((ext_vector_type(4)));

// ---- bf16 helpers (manual, bit-exact) ----
__device__ __forceinline__ float blo(unsigned int u) {
    union { unsigned int i; float f; } x; x.i = u << 16; return x.f;
}
__device__ __forceinline__ float bhi(unsigned int u) {
    union { unsigned int i; float f; } x; x.i = u & 0xffff0000u; return x.f;
}
__device__ __forceinline__ unsigned short f2b(float f) {   // round-to-nearest-even
    union { float f; unsigned int i; } x; x.f = f;
    unsigned int r = x.i + 0x7fffu + ((x.i >> 16) & 1u);
    return (unsigned short)(r >> 16);
}

// ---- async global->LDS, 16B/lane. Per-lane GLOBAL address is allowed (gather);
// ---- LDS side is wave-uniform base + lane*16.
__device__ __forceinline__ void gload_lds16(const void* g, void* l) {
    __builtin_amdgcn_global_load_lds(
        (const __attribute__((address_space(1))) unsigned int*)g,
        (__attribute__((address_space(3))) unsigned int*)l, 16, 0, 0);
}

// ---------------- LayerNorm: one block per row; fp32 in -> bf16 out ----------------
__global__ __launch_bounds__(256) void ln_kernel(const float* __restrict__ x,
                                                 const float* __restrict__ g,
                                                 const float* __restrict__ b,
                                                 unsigned short* __restrict__ out) {
    int row = blockIdx.x;
    const float* xr = x + (size_t)row * DIM;
    unsigned short* orow = out + (size_t)row * DIM;
    int t = threadIdx.x;
    float4 v = *((const float4*)(xr + t * 4));
    float s  = v.x + v.y + v.z + v.w;
    float ss = v.x * v.x + v.y * v.y + v.z * v.z + v.w * v.w;
    __shared__ float red1[256], red2[256];
    red1[t] = s; red2[t] = ss;
    __syncthreads();
    for (int off = 128; off > 0; off >>= 1) {
        if (t < off) { red1[t] += red1[t + off]; red2[t] += red2[t + off]; }
        __syncthreads();
    }
    float mu   = red1[0] * (1.0f / DIM);
    float var  = red2[0] * (1.0f / DIM) - mu * mu;
    float rstd = rsqrtf(var + 1e-5f);
    float4 gv = *((const float4*)(g + t * 4));
    float4 bv = *((const float4*)(b + t * 4));
    ushort4 o;
    o.x = f2b((v.x - mu) * rstd * gv.x + bv.x);
    o.y = f2b((v.y - mu) * rstd * gv.y + bv.y);
    o.z = f2b((v.z - mu) * rstd * gv.z + bv.z);
    o.w = f2b((v.w - mu) * rstd * gv.w + bv.w);
    *((ushort4*)(orow + t * 4)) = o;
}

// ------------- Weight convert+transpose: W fp32 [K,N] -> Wt bf16 [N,K] -------------
__global__ __launch_bounds__(256) void wconv_t(const float* __restrict__ W,
                                               unsigned short* __restrict__ Wt,
                                               int K, int N) {
    __shared__ unsigned short T[64][68];
    int t = threadIdx.x;
    int n0 = blockIdx.x * 64, k0 = blockIdx.y * 64;
    int cr = t >> 4;
    int cc = (t & 15) * 4;
    #pragma unroll
    for (int r = 0; r < 4; ++r) {
        int kk = cr + 16 * r;
        float4 v = *((const float4*)(W + (size_t)(k0 + kk) * N + n0 + cc));
        T[cc + 0][kk] = f2b(v.x);
        T[cc + 1][kk] = f2b(v.y);
        T[cc + 2][kk] = f2b(v.z);
        T[cc + 3][kk] = f2b(v.w);
    }
    __syncthreads();
    #pragma unroll
    for (int r = 0; r < 4; ++r) {
        int nn = cr + 16 * r;
        *((ushort4*)(Wt + (size_t)(n0 + nn) * K + k0 + cc)) = *((ushort4*)&T[nn][cc]);
    }
}

// ---------------- MFMA GEMM: C = A[M,K](bf16) @ Bt[N,K]^T(bf16) + bias ----------------
// fuse: 0 = bias, bf16 out; 1 = bias+GELU, bf16 out; 2 = bias+residual(fp32), fp32 out
__global__ __launch_bounds__(256) void mfma_gemm(const unsigned short* __restrict__ A,
                                                 const unsigned short* __restrict__ Bt,
                                                 const float* __restrict__ bias,
                                                 const float* __restrict__ add,
                                                 void* __restrict__ Cout,
                                                 int M, int N, int K, int fuse) {
    __shared__ __align__(16) short Asm[8192];
    __shared__ __align__(16) short Bsm[8192];

    const int tid  = threadIdx.x;
    const int lane = tid & 63;
    const int wave = tid >> 6;
    const int wy = wave >> 1, wx = wave & 1;
    const int lr = lane & 15;
    const int lq = lane >> 4;
    const int m0 = blockIdx.y * 128, n0 = blockIdx.x * 128;

    f32x4 acc[4][4];
    #pragma unroll
    for (int i = 0; i < 4; ++i)
        #pragma unroll
        for (int j = 0; j < 4; ++j)
            acc[i][j] = (f32x4){0.f, 0.f, 0.f, 0.f};

    const unsigned short* ag[4]; const unsigned short* bg[4];
    short* al[4]; short* bl[4];
    #pragma unroll
    for (int j = 0; j < 4; ++j) {
        int cid = wave * 4 + j;
        int rb  = (cid >> 1) * 16 + lr;
        int kk  = (cid & 1) * 32 + lq * 8;
        ag[j] = A  + (size_t)(m0 + rb) * K + kk;
        bg[j] = Bt + (size_t)(n0 + rb) * K + kk;
        al[j] = &Asm[cid * 512];
        bl[j] = &Bsm[cid * 512];
    }

    for (int k0 = 0; k0 < K; k0 += 64) {
        #pragma unroll
        for (int j = 0; j < 4; ++j) {
            gload_lds16(ag[j], al[j]);
            gload_lds16(bg[j], bl[j]);
            ag[j] += 64; bg[j] += 64;
        }
        __syncthreads();
        #pragma unroll
        for (int kc = 0; kc < 2; ++kc) {
            s16x8 af[4], bf[4];
            #pragma unroll
            for (int i = 0; i < 4; ++i)
                af[i] = *((const s16x8*)&Asm[((wy * 4 + i) * 2 + kc) * 512 + lane * 8]);
            #pragma unroll
            for (int j = 0; j < 4; ++j)
                bf[j] = *((const s16x8*)&Bsm[((wx * 4 + j) * 2 + kc) * 512 + lane * 8]);
            #pragma unroll
            for (int i = 0; i < 4; ++i)
                #pragma unroll
                for (int j = 0; j < 4; ++j)
                    acc[i][j] = __builtin_amdgcn_mfma_f32_16x16x32_bf16(af[i], bf[j], acc[i][j], 0, 0, 0);
        }
        __syncthreads();
    }

    #pragma unroll
    for (int j = 0; j < 4; ++j) {
        int col = n0 + wx * 64 + j * 16 + lr;
        float bi = bias[col];
        #pragma unroll
        for (int i = 0; i < 4; ++i) {
            int row0 = m0 + wy * 64 + i * 16 + lq * 4;
            #pragma unroll
            for (int r = 0; r < 4; ++r) {
                float val = acc[i][j][r] + bi;
                size_t idx = (size_t)(row0 + r) * N + col;
                if (fuse == 2) {
                    ((float*)Cout)[idx] = val + add[idx];
                } else {
                    if (fuse == 1)
                        val = 0.5f * val * (1.0f + erff(val * 0.70710678f));
                    ((unsigned short*)Cout)[idx] = f2b(val);
                }
            }
        }
    }
}

// ------------- V transpose: qkv [B,N,3,H,64] -> Vt [BH][64 d][SEQ] (bf16) -------------
__global__ __launch_bounds__(256) void vtrans_kernel(const unsigned short* __restrict__ qkv,
                                                     unsigned short* __restrict__ Vt) {
    __shared__ unsigned short T[64][72];   // [token][d], pad 72 (row=144B, 16B-aligned)
    int bh = blockIdx.y; int b = bh >> 4, h = bh & 15;
    int t0 = blockIdx.x * 64;
    int tid = threadIdx.x;
    {
        int i = tid >> 2;             // token 0..63
        int c = (tid & 3) * 16;       // d0
        const unsigned short* src = qkv + ((size_t)(b * SEQ + t0 + i)) * (3 * DIM) + 2 * DIM + h * 64 + c;
        *((uint4*)&T[i][c])     = *((const uint4*)src);
        *((uint4*)&T[i][c + 8]) = *((const uint4*)(src + 8));
    }
    __syncthreads();
    {
        int d  = tid >> 2;            // 0..63
        int kg = (tid & 3) * 16;
        unsigned short pk[16];
        #pragma unroll
        for (int j = 0; j < 16; ++j) pk[j] = T[kg + j][d];
        unsigned short* dst = Vt + ((size_t)bh * 64 + d) * SEQ + t0 + kg;
        *((uint4*)dst)       = *((uint4*)&pk[0]);
        *((uint4*)(dst + 8)) = *((uint4*)&pk[8]);
    }
}

// ------------- MFMA flash attention: block = (bh) x 128-q tile, 4 waves -------------
// Q,K staged straight from qkv (gather via global_load_lds); V from Vt [bh][d][SEQ].
// S and PV on mfma_f32_16x16x32_bf16; P through LDS (wave-private rows, no barrier).
// Softmax scale 0.125 folded into exp args (row stats kept on raw S).
__global__ __launch_bounds__(256) void fattn_mfma(const unsigned short* __restrict__ qkv,
                                                  const unsigned short* __restrict__ Vt,
                                                  unsigned short* __restrict__ out) {
    __shared__ __align__(16) short Qs[8192];     // 16 chunks x 512 bf16 (128q x 64d)
    __shared__ __align__(16) short Ks[4096];     // 8 chunks (64k x 64d)
    __shared__ __align__(16) short Vs[4096];     // 8 chunks (Vt rows: 64d x 64k)
    __shared__ __align__(16) short Ps[128 * 72]; // P row-major [q][k], pad 72

    const int tid = threadIdx.x, lane = tid & 63, wave = tid >> 6;
    const int lr = lane & 15, lq = lane >> 4;
    const int bh = blockIdx.y, b = bh >> 4, h = bh & 15;
    const int q0 = blockIdx.x * 128;

    // stage Q once: chunk cid = rb*2+kh; wave stages cid = wave*4+j (its own 2 m-blocks)
    #pragma unroll
    for (int j = 0; j < 4; ++j) {
        int cid = wave * 4 + j;
        const unsigned short* g = qkv + ((size_t)(b * SEQ + q0 + 16 * (cid >> 1) + lr)) * (3 * DIM)
                                  + h * 64 + (cid & 1) * 32 + lq * 8;
        gload_lds16(g, &Qs[cid * 512]);
    }

    const unsigned short* kg_[2]; const unsigned short* vg_[2];
    short *kl_[2], *vl_[2];
    #pragma unroll
    for (int j = 0; j < 2; ++j) {
        int cid = wave * 2 + j;
        kg_[j] = qkv + ((size_t)(b * SEQ + 16 * (cid >> 1) + lr)) * (3 * DIM)
                 + DIM + h * 64 + (cid & 1) * 32 + lq * 8;
        vg_[j] = Vt + ((size_t)(bh * 64 + 16 * (cid >> 1) + lr)) * SEQ + (cid & 1) * 32 + lq * 8;
        kl_[j] = &Ks[cid * 512];
        vl_[j] = &Vs[cid * 512];
    }

    f32x4 osum[2][4];
    float mrow[2][4], lrow[2][4];
    #pragma unroll
    for (int i = 0; i < 2; ++i)
        #pragma unroll
        for (int d = 0; d < 4; ++d) {
            osum[i][d] = (f32x4){0.f, 0.f, 0.f, 0.f};
            mrow[i][d] = -1e30f; lrow[i][d] = 0.f;
        }

    for (int k0 = 0; k0 < SEQ; k0 += 64) {
        #pragma unroll
        for (int j = 0; j < 2; ++j) {
            gload_lds16(kg_[j], kl_[j]);
            gload_lds16(vg_[j], vl_[j]);
            kg_[j] += 64 * 3 * DIM;
            vg_[j] += 64;
        }
        __syncthreads();

        // S = Q K^T   (m-blocks mb = wave*2+i)
        f32x4 s[2][4];
        #pragma unroll
        for (int i = 0; i < 2; ++i)
            #pragma unroll
            for (int jb = 0; jb < 4; ++jb)
                s[i][jb] = (f32x4){0.f, 0.f, 0.f, 0.f};
        #pragma unroll
        for (int kc = 0; kc < 2; ++kc) {
            s16x8 aq0 = *((const s16x8*)&Qs[(wave * 4 + 0 + kc) * 512 + lane * 8]);
            s16x8 aq1 = *((const s16x8*)&Qs[(wave * 4 + 2 + kc) * 512 + lane * 8]);
            #pragma unroll
            for (int jb = 0; jb < 4; ++jb) {
                s16x8 bk = *((const s16x8*)&Ks[(jb * 2 + kc) * 512 + lane * 8]);
                s[0][jb] = __builtin_amdgcn_mfma_f32_16x16x32_bf16(aq0, bk, s[0][jb], 0, 0, 0);
                s[1][jb] = __builtin_amdgcn_mfma_f32_16x16x32_bf16(aq1, bk, s[1][jb], 0, 0, 0);
            }
        }

        // online softmax on raw S (scale folded into exp); write P rows (wave-private)
        #pragma unroll
        for (int i = 0; i < 2; ++i) {
            #pragma unroll
            for (int r = 0; r < 4; ++r) {
                float mx = fmaxf(fmaxf(s[i][0][r], s[i][1][r]), fmaxf(s[i][2][r], s[i][3][r]));
                mx = fmaxf(mx, __shfl_xor(mx, 1, 64));
                mx = fmaxf(mx, __shfl_xor(mx, 2, 64));
                mx = fmaxf(mx, __shfl_xor(mx, 4, 64));
                mx = fmaxf(mx, __shfl_xor(mx, 8, 64));
                float mn = fmaxf(mrow[i][r], mx);
                float al = __expf(0.125f * (mrow[i][r] - mn));
                mrow[i][r] = mn;
                float rs = 0.f;
                int prow = (wave * 2 + i) * 16 + lq * 4 + r;
                #pragma unroll
                for (int jb = 0; jb < 4; ++jb) {
                    float p = __expf(0.125f * (s[i][jb][r] - mn));
                    rs += p;
                    Ps[prow * 72 + jb * 16 + lr] = (short)f2b(p);
                }
                rs += __shfl_xor(rs, 1, 64);
                rs += __shfl_xor(rs, 2, 64);
                rs += __shfl_xor(rs, 4, 64);
                rs += __shfl_xor(rs, 8, 64);
                lrow[i][r] = lrow[i][r] * al + rs;
                #pragma unroll
                for (int db = 0; db < 4; ++db) osum[i][db][r] *= al;
            }
        }

        // O += P V  (P rows are wave-private; LDS ops per wave are in-order -> no barrier)
        #pragma unroll
        for (int kc = 0; kc < 2; ++kc) {
            s16x8 ap0 = *((const s16x8*)&Ps[((wave * 2 + 0) * 16 + lr) * 72 + kc * 32 + lq * 8]);
            s16x8 ap1 = *((const s16x8*)&Ps[((wave * 2 + 1) * 16 + lr) * 72 + kc * 32 + lq * 8]);
            #pragma unroll
            for (int db = 0; db < 4; ++db) {
                s16x8 bv = *((const s16x8*)&Vs[(db * 2 + kc) * 512 + lane * 8]);
                osum[0][db] = __builtin_amdgcn_mfma_f32_16x16x32_bf16(ap0, bv, osum[0][db], 0, 0, 0);
                osum[1][db] = __builtin_amdgcn_mfma_f32_16x16x32_bf16(ap1, bv, osum[1][db], 0, 0, 0);
            }
        }
        __syncthreads();   // before next tile overwrites Ks/Vs
    }

    // epilogue: O/l -> out [B,N,H*64] bf16
    #pragma unroll
    for (int i = 0; i < 2; ++i) {
        int qrow = q0 + (wave * 2 + i) * 16 + lq * 4;
        #pragma unroll
        for (int r = 0; r < 4; ++r) {
            float inv = 1.0f / lrow[i][r];
            size_t rowoff = ((size_t)(b * SEQ + qrow + r)) * DIM + h * 64;
            #pragma unroll
            for (int db = 0; db < 4; ++db)
                out[rowoff + db * 16 + lr] = f2b(osum[i][db][r] * inv);
        }
    }
}

extern "C" void kernel_launch(void* const* d_in, const int* in_sizes, int n_in,
                              void* d_out, int out_size, void* d_ws, size_t ws_size,
                              hipStream_t stream) {
    const float* x      = (const float*)d_in[0];
    const float* ln1_g  = (const float*)d_in[1];
    const float* ln1_b  = (const float*)d_in[2];
    const float* ln2_g  = (const float*)d_in[3];
    const float* ln2_b  = (const float*)d_in[4];
    const float* qkv_w  = (const float*)d_in[5];
    const float* qkv_b  = (const float*)d_in[6];
    const float* proj_w = (const float*)d_in[7];
    const float* proj_b = (const float*)d_in[8];
    const float* fc1_w  = (const float*)d_in[9];
    const float* fc1_b  = (const float*)d_in[10];
    const float* fc2_w  = (const float*)d_in[11];
    const float* fc2_b  = (const float*)d_in[12];
    float* out = (float*)d_out;

    // workspace layout (MiB offsets): wT 0..24, lnout 24..32, attnout 32..40,
    // bigbuf 40..72 (qkv bf16 = first 24 MiB; Vt = last 8 MiB; gelu reuses all 32)
    char* ws = (char*)d_ws;
    unsigned short* wT_qkv  = (unsigned short*)(ws);
    unsigned short* wT_proj = (unsigned short*)(ws + (6u  << 20));
    unsigned short* wT_fc1  = (unsigned short*)(ws + (8u  << 20));
    unsigned short* wT_fc2  = (unsigned short*)(ws + (16u << 20));
    unsigned short* lnout   = (unsigned short*)(ws + (24u << 20));
    unsigned short* attnout = (unsigned short*)(ws + (32u << 20));
    unsigned short* bigbuf  = (unsigned short*)(ws + (40u << 20));
    unsigned short* Vt      = (unsigned short*)(ws + (64u << 20));   // bigbuf+24MiB

    // 0) weight convert+transpose to bf16 [N,K]
    wconv_t<<<dim3(3 * DIM / 64, DIM / 64), 256, 0, stream>>>(qkv_w, wT_qkv, DIM, 3 * DIM);
    wconv_t<<<dim3(DIM / 64, DIM / 64), 256, 0, stream>>>(proj_w, wT_proj, DIM, DIM);
    wconv_t<<<dim3(HIDDEN / 64, DIM / 64), 256, 0, stream>>>(fc1_w, wT_fc1, DIM, HIDDEN);
    wconv_t<<<dim3(DIM / 64, HIDDEN / 64), 256, 0, stream>>>(fc2_w, wT_fc2, HIDDEN, DIM);

    // 1) h1 = LN1(x) -> bf16
    ln_kernel<<<ROWS, 256, 0, stream>>>(x, ln1_g, ln1_b, lnout);
    // 2) qkv = h1 @ qkv_w + qkv_b -> bf16   [4096 x 3072]
    mfma_gemm<<<dim3(3 * DIM / 128, ROWS / 128), 256, 0, stream>>>(
        lnout, wT_qkv, qkv_b, nullptr, bigbuf, ROWS, 3 * DIM, DIM, 0);
    // 2b) Vt = transpose(V)
    vtrans_kernel<<<dim3(SEQ / 64, BATCH * HEADS), 256, 0, stream>>>(bigbuf, Vt);
    // 3) o = mfma flash attention -> bf16
    fattn_mfma<<<dim3(SEQ / 128, BATCH * HEADS), 256, 0, stream>>>(bigbuf, Vt, attnout);
    // 4) x1 = x + o @ proj_w + proj_b -> d_out (fp32)
    mfma_gemm<<<dim3(DIM / 128, ROWS / 128), 256, 0, stream>>>(
        attnout, wT_proj, proj_b, x, out, ROWS, DIM, DIM, 2);
    // 5) h2 = LN2(x1) -> bf16
    ln_kernel<<<ROWS, 256, 0, stream>>>(out, ln2_g, ln2_b, lnout);
    // 6) g = gelu(h2 @ fc1_w + fc1_b) -> bf16  [4096 x 4096]
    mfma_gemm<<<dim3(HIDDEN / 128, ROWS / 128), 256, 0, stream>>>(
        lnout, wT_fc1, fc1_b, nullptr, bigbuf, ROWS, HIDDEN, DIM, 1);
    // 7) out = x1 + g @ fc2_w + fc2_b -> d_out (fp32)
    mfma_gemm<<<dim3(DIM / 128, ROWS / 128), 256, 0, stream>>>(
        bigbuf, wT_fc2, fc2_b, out, out, ROWS, DIM, HIDDEN, 2);
}

// Round 5
// 523.867 us; speedup vs baseline: 10.6855x; 1.0153x over previous
//
#include <hip/hip_runtime.h>
#include <math.h>

#define DIM    1024
#define HEADS  16
#define HDIM   64
#define HIDDEN 4096
#define BATCH  4
#define SEQ    1024
#define ROWS   (BATCH * SEQ)   // 4096

typedef short s16x8 __attribute__((ext_vector_type(8)));
typedef float f32x4 __attribute__((ext_vector_type(4)));

// ---- bf16 helpers (manual, bit-exact) ----
__device__ __forceinline__ float blo(unsigned int u) {
    union { unsigned int i; float f; } x; x.i = u << 16; return x.f;
}
__device__ __forceinline__ float bhi(unsigned int u) {
    union { unsigned int i; float f; } x; x.i = u & 0xffff0000u; return x.f;
}
__device__ __forceinline__ unsigned short f2b(float f) {   // round-to-nearest-even
    union { float f; unsigned int i; } x; x.f = f;
    unsigned int r = x.i + 0x7fffu + ((x.i >> 16) & 1u);
    return (unsigned short)(r >> 16);
}

// ---- async global->LDS, 16B/lane. Per-lane GLOBAL address (gather);
// ---- LDS side is wave-uniform base + lane*16.
__device__ __forceinline__ void gload_lds16(const void* g, void* l) {
    __builtin_amdgcn_global_load_lds(
        (const __attribute__((address_space(1))) unsigned int*)g,
        (__attribute__((address_space(3))) unsigned int*)l, 16, 0, 0);
}

// ---------------- LayerNorm: one block per row; fp32 in -> bf16 out ----------------
__global__ __launch_bounds__(256) void ln_kernel(const float* __restrict__ x,
                                                 const float* __restrict__ g,
                                                 const float* __restrict__ b,
                                                 unsigned short* __restrict__ out) {
    int row = blockIdx.x;
    const float* xr = x + (size_t)row * DIM;
    unsigned short* orow = out + (size_t)row * DIM;
    int t = threadIdx.x;
    float4 v = *((const float4*)(xr + t * 4));
    float s  = v.x + v.y + v.z + v.w;
    float ss = v.x * v.x + v.y * v.y + v.z * v.z + v.w * v.w;
    __shared__ float red1[256], red2[256];
    red1[t] = s; red2[t] = ss;
    __syncthreads();
    for (int off = 128; off > 0; off >>= 1) {
        if (t < off) { red1[t] += red1[t + off]; red2[t] += red2[t + off]; }
        __syncthreads();
    }
    float mu   = red1[0] * (1.0f / DIM);
    float var  = red2[0] * (1.0f / DIM) - mu * mu;
    float rstd = rsqrtf(var + 1e-5f);
    float4 gv = *((const float4*)(g + t * 4));
    float4 bv = *((const float4*)(b + t * 4));
    ushort4 o;
    o.x = f2b((v.x - mu) * rstd * gv.x + bv.x);
    o.y = f2b((v.y - mu) * rstd * gv.y + bv.y);
    o.z = f2b((v.z - mu) * rstd * gv.z + bv.z);
    o.w = f2b((v.w - mu) * rstd * gv.w + bv.w);
    *((ushort4*)(orow + t * 4)) = o;
}

// ------------- Weight convert+transpose: W fp32 [K,N] -> Wt bf16 [N,K] -------------
__global__ __launch_bounds__(256) void wconv_t(const float* __restrict__ W,
                                               unsigned short* __restrict__ Wt,
                                               int K, int N) {
    __shared__ unsigned short T[64][68];
    int t = threadIdx.x;
    int n0 = blockIdx.x * 64, k0 = blockIdx.y * 64;
    int cr = t >> 4;
    int cc = (t & 15) * 4;
    #pragma unroll
    for (int r = 0; r < 4; ++r) {
        int kk = cr + 16 * r;
        float4 v = *((const float4*)(W + (size_t)(k0 + kk) * N + n0 + cc));
        T[cc + 0][kk] = f2b(v.x);
        T[cc + 1][kk] = f2b(v.y);
        T[cc + 2][kk] = f2b(v.z);
        T[cc + 3][kk] = f2b(v.w);
    }
    __syncthreads();
    #pragma unroll
    for (int r = 0; r < 4; ++r) {
        int nn = cr + 16 * r;
        *((ushort4*)(Wt + (size_t)(n0 + nn) * K + k0 + cc)) = *((ushort4*)&T[nn][cc]);
    }
}

// ---------------- MFMA GEMM (double-buffered): C = A[M,K] @ Bt[N,K]^T + bias ----------------
// fuse: 0 = bias, bf16 out; 1 = bias+GELU, bf16 out; 2 = bias+residual(fp32), fp32 out
// 128x128 tile, BK=64, 4 waves (2x2), each 4x4 of mfma_f32_16x16x32_bf16.
// Ping-pong LDS: one barrier per K-iter; tile t+1's global_load_lds issued right
// after the barrier so compute(t) shadows the load latency (key at 1 block/CU).
// Grid: blockIdx.x = m-block (fastest) so same-XCD blocks share A rows (L2 reuse).
__global__ __launch_bounds__(256) void mfma_gemm(const unsigned short* __restrict__ A,
                                                 const unsigned short* __restrict__ Bt,
                                                 const float* __restrict__ bias,
                                                 const float* __restrict__ add,
                                                 void* __restrict__ Cout,
                                                 int M, int N, int K, int fuse) {
    __shared__ __align__(16) short Asm[2][8192];   // 2 x 16 KB
    __shared__ __align__(16) short Bsm[2][8192];

    const int tid  = threadIdx.x;
    const int lane = tid & 63;
    const int wave = tid >> 6;
    const int wy = wave >> 1, wx = wave & 1;
    const int lr = lane & 15;
    const int lq = lane >> 4;
    const int m0 = blockIdx.x * 128, n0 = blockIdx.y * 128;   // m fastest

    f32x4 acc[4][4];
    #pragma unroll
    for (int i = 0; i < 4; ++i)
        #pragma unroll
        for (int j = 0; j < 4; ++j)
            acc[i][j] = (f32x4){0.f, 0.f, 0.f, 0.f};

    const unsigned short* ag[4]; const unsigned short* bg[4];
    #pragma unroll
    for (int j = 0; j < 4; ++j) {
        int cid = wave * 4 + j;
        int rb  = (cid >> 1) * 16 + lr;
        int kk  = (cid & 1) * 32 + lq * 8;
        ag[j] = A  + (size_t)(m0 + rb) * K + kk;
        bg[j] = Bt + (size_t)(n0 + rb) * K + kk;
    }

    // prologue: stage tile 0 into buffer 0
    #pragma unroll
    for (int j = 0; j < 4; ++j) {
        int cid = wave * 4 + j;
        gload_lds16(ag[j], &Asm[0][cid * 512]);
        gload_lds16(bg[j], &Bsm[0][cid * 512]);
        ag[j] += 64; bg[j] += 64;
    }

    const int nt = K >> 6;
    for (int t = 0; t < nt; ++t) {
        const int cur = t & 1;
        __syncthreads();                  // drains loads for buffer `cur`
        if (t + 1 < nt) {                 // prefetch next tile into other buffer
            #pragma unroll
            for (int j = 0; j < 4; ++j) {
                int cid = wave * 4 + j;
                gload_lds16(ag[j], &Asm[cur ^ 1][cid * 512]);
                gload_lds16(bg[j], &Bsm[cur ^ 1][cid * 512]);
                ag[j] += 64; bg[j] += 64;
            }
        }
        #pragma unroll
        for (int kc = 0; kc < 2; ++kc) {
            s16x8 af[4], bf[4];
            #pragma unroll
            for (int i = 0; i < 4; ++i)
                af[i] = *((const s16x8*)&Asm[cur][((wy * 4 + i) * 2 + kc) * 512 + lane * 8]);
            #pragma unroll
            for (int j = 0; j < 4; ++j)
                bf[j] = *((const s16x8*)&Bsm[cur][((wx * 4 + j) * 2 + kc) * 512 + lane * 8]);
            #pragma unroll
            for (int i = 0; i < 4; ++i)
                #pragma unroll
                for (int j = 0; j < 4; ++j)
                    acc[i][j] = __builtin_amdgcn_mfma_f32_16x16x32_bf16(af[i], bf[j], acc[i][j], 0, 0, 0);
        }
    }

    #pragma unroll
    for (int j = 0; j < 4; ++j) {
        int col = n0 + wx * 64 + j * 16 + lr;
        float bi = bias[col];
        #pragma unroll
        for (int i = 0; i < 4; ++i) {
            int row0 = m0 + wy * 64 + i * 16 + lq * 4;
            #pragma unroll
            for (int r = 0; r < 4; ++r) {
                float val = acc[i][j][r] + bi;
                size_t idx = (size_t)(row0 + r) * N + col;
                if (fuse == 2) {
                    ((float*)Cout)[idx] = val + add[idx];
                } else {
                    if (fuse == 1)
                        val = 0.5f * val * (1.0f + erff(val * 0.70710678f));
                    ((unsigned short*)Cout)[idx] = f2b(val);
                }
            }
        }
    }
}

// ------------- V transpose: qkv [B,N,3,H,64] -> Vt [BH][64 d][SEQ] (bf16) -------------
__global__ __launch_bounds__(256) void vtrans_kernel(const unsigned short* __restrict__ qkv,
                                                     unsigned short* __restrict__ Vt) {
    __shared__ unsigned short T[64][72];
    int bh = blockIdx.y; int b = bh >> 4, h = bh & 15;
    int t0 = blockIdx.x * 64;
    int tid = threadIdx.x;
    {
        int i = tid >> 2;
        int c = (tid & 3) * 16;
        const unsigned short* src = qkv + ((size_t)(b * SEQ + t0 + i)) * (3 * DIM) + 2 * DIM + h * 64 + c;
        *((uint4*)&T[i][c])     = *((const uint4*)src);
        *((uint4*)&T[i][c + 8]) = *((const uint4*)(src + 8));
    }
    __syncthreads();
    {
        int d  = tid >> 2;
        int kg = (tid & 3) * 16;
        unsigned short pk[16];
        #pragma unroll
        for (int j = 0; j < 16; ++j) pk[j] = T[kg + j][d];
        unsigned short* dst = Vt + ((size_t)bh * 64 + d) * SEQ + t0 + kg;
        *((uint4*)dst)       = *((uint4*)&pk[0]);
        *((uint4*)(dst + 8)) = *((uint4*)&pk[8]);
    }
}

// ------------- MFMA flash attention: block = (bh) x 128-q tile, 4 waves -------------
__global__ __launch_bounds__(256) void fattn_mfma(const unsigned short* __restrict__ qkv,
                                                  const unsigned short* __restrict__ Vt,
                                                  unsigned short* __restrict__ out) {
    __shared__ __align__(16) short Qs[8192];
    __shared__ __align__(16) short Ks[4096];
    __shared__ __align__(16) short Vs[4096];
    __shared__ __align__(16) short Ps[128 * 72];

    const int tid = threadIdx.x, lane = tid & 63, wave = tid >> 6;
    const int lr = lane & 15, lq = lane >> 4;
    const int bh = blockIdx.y, b = bh >> 4, h = bh & 15;
    const int q0 = blockIdx.x * 128;

    #pragma unroll
    for (int j = 0; j < 4; ++j) {
        int cid = wave * 4 + j;
        const unsigned short* g = qkv + ((size_t)(b * SEQ + q0 + 16 * (cid >> 1) + lr)) * (3 * DIM)
                                  + h * 64 + (cid & 1) * 32 + lq * 8;
        gload_lds16(g, &Qs[cid * 512]);
    }

    const unsigned short* kg_[2]; const unsigned short* vg_[2];
    short *kl_[2], *vl_[2];
    #pragma unroll
    for (int j = 0; j < 2; ++j) {
        int cid = wave * 2 + j;
        kg_[j] = qkv + ((size_t)(b * SEQ + 16 * (cid >> 1) + lr)) * (3 * DIM)
                 + DIM + h * 64 + (cid & 1) * 32 + lq * 8;
        vg_[j] = Vt + ((size_t)(bh * 64 + 16 * (cid >> 1) + lr)) * SEQ + (cid & 1) * 32 + lq * 8;
        kl_[j] = &Ks[cid * 512];
        vl_[j] = &Vs[cid * 512];
    }

    f32x4 osum[2][4];
    float mrow[2][4], lrow[2][4];
    #pragma unroll
    for (int i = 0; i < 2; ++i)
        #pragma unroll
        for (int d = 0; d < 4; ++d) {
            osum[i][d] = (f32x4){0.f, 0.f, 0.f, 0.f};
            mrow[i][d] = -1e30f; lrow[i][d] = 0.f;
        }

    for (int k0 = 0; k0 < SEQ; k0 += 64) {
        #pragma unroll
        for (int j = 0; j < 2; ++j) {
            gload_lds16(kg_[j], kl_[j]);
            gload_lds16(vg_[j], vl_[j]);
            kg_[j] += 64 * 3 * DIM;
            vg_[j] += 64;
        }
        __syncthreads();

        f32x4 s[2][4];
        #pragma unroll
        for (int i = 0; i < 2; ++i)
            #pragma unroll
            for (int jb = 0; jb < 4; ++jb)
                s[i][jb] = (f32x4){0.f, 0.f, 0.f, 0.f};
        #pragma unroll
        for (int kc = 0; kc < 2; ++kc) {
            s16x8 aq0 = *((const s16x8*)&Qs[(wave * 4 + 0 + kc) * 512 + lane * 8]);
            s16x8 aq1 = *((const s16x8*)&Qs[(wave * 4 + 2 + kc) * 512 + lane * 8]);
            #pragma unroll
            for (int jb = 0; jb < 4; ++jb) {
                s16x8 bk = *((const s16x8*)&Ks[(jb * 2 + kc) * 512 + lane * 8]);
                s[0][jb] = __builtin_amdgcn_mfma_f32_16x16x32_bf16(aq0, bk, s[0][jb], 0, 0, 0);
                s[1][jb] = __builtin_amdgcn_mfma_f32_16x16x32_bf16(aq1, bk, s[1][jb], 0, 0, 0);
            }
        }

        #pragma unroll
        for (int i = 0; i < 2; ++i) {
            #pragma unroll
            for (int r = 0; r < 4; ++r) {
                float mx = fmaxf(fmaxf(s[i][0][r], s[i][1][r]), fmaxf(s[i][2][r], s[i][3][r]));
                mx = fmaxf(mx, __shfl_xor(mx, 1, 64));
                mx = fmaxf(mx, __shfl_xor(mx, 2, 64));
                mx = fmaxf(mx, __shfl_xor(mx, 4, 64));
                mx = fmaxf(mx, __shfl_xor(mx, 8, 64));
                float mn = fmaxf(mrow[i][r], mx);
                float al = __expf(0.125f * (mrow[i][r] - mn));
                mrow[i][r] = mn;
                float rs = 0.f;
                int prow = (wave * 2 + i) * 16 + lq * 4 + r;
                #pragma unroll
                for (int jb = 0; jb < 4; ++jb) {
                    float p = __expf(0.125f * (s[i][jb][r] - mn));
                    rs += p;
                    Ps[prow * 72 + jb * 16 + lr] = (short)f2b(p);
                }
                rs += __shfl_xor(rs, 1, 64);
                rs += __shfl_xor(rs, 2, 64);
                rs += __shfl_xor(rs, 4, 64);
                rs += __shfl_xor(rs, 8, 64);
                lrow[i][r] = lrow[i][r] * al + rs;
                #pragma unroll
                for (int db = 0; db < 4; ++db) osum[i][db][r] *= al;
            }
        }

        #pragma unroll
        for (int kc = 0; kc < 2; ++kc) {
            s16x8 ap0 = *((const s16x8*)&Ps[((wave * 2 + 0) * 16 + lr) * 72 + kc * 32 + lq * 8]);
            s16x8 ap1 = *((const s16x8*)&Ps[((wave * 2 + 1) * 16 + lr) * 72 + kc * 32 + lq * 8]);
            #pragma unroll
            for (int db = 0; db < 4; ++db) {
                s16x8 bv = *((const s16x8*)&Vs[(db * 2 + kc) * 512 + lane * 8]);
                osum[0][db] = __builtin_amdgcn_mfma_f32_16x16x32_bf16(ap0, bv, osum[0][db], 0, 0, 0);
                osum[1][db] = __builtin_amdgcn_mfma_f32_16x16x32_bf16(ap1, bv, osum[1][db], 0, 0, 0);
            }
        }
        __syncthreads();
    }

    #pragma unroll
    for (int i = 0; i < 2; ++i) {
        int qrow = q0 + (wave * 2 + i) * 16 + lq * 4;
        #pragma unroll
        for (int r = 0; r < 4; ++r) {
            float inv = 1.0f / lrow[i][r];
            size_t rowoff = ((size_t)(b * SEQ + qrow + r)) * DIM + h * 64;
            #pragma unroll
            for (int db = 0; db < 4; ++db)
                out[rowoff + db * 16 + lr] = f2b(osum[i][db][r] * inv);
        }
    }
}

extern "C" void kernel_launch(void* const* d_in, const int* in_sizes, int n_in,
                              void* d_out, int out_size, void* d_ws, size_t ws_size,
                              hipStream_t stream) {
    const float* x      = (const float*)d_in[0];
    const float* ln1_g  = (const float*)d_in[1];
    const float* ln1_b  = (const float*)d_in[2];
    const float* ln2_g  = (const float*)d_in[3];
    const float* ln2_b  = (const float*)d_in[4];
    const float* qkv_w  = (const float*)d_in[5];
    const float* qkv_b  = (const float*)d_in[6];
    const float* proj_w = (const float*)d_in[7];
    const float* proj_b = (const float*)d_in[8];
    const float* fc1_w  = (const float*)d_in[9];
    const float* fc1_b  = (const float*)d_in[10];
    const float* fc2_w  = (const float*)d_in[11];
    const float* fc2_b  = (const float*)d_in[12];
    float* out = (float*)d_out;

    char* ws = (char*)d_ws;
    unsigned short* wT_qkv  = (unsigned short*)(ws);
    unsigned short* wT_proj = (unsigned short*)(ws + (6u  << 20));
    unsigned short* wT_fc1  = (unsigned short*)(ws + (8u  << 20));
    unsigned short* wT_fc2  = (unsigned short*)(ws + (16u << 20));
    unsigned short* lnout   = (unsigned short*)(ws + (24u << 20));
    unsigned short* attnout = (unsigned short*)(ws + (32u << 20));
    unsigned short* bigbuf  = (unsigned short*)(ws + (40u << 20));
    unsigned short* Vt      = (unsigned short*)(ws + (64u << 20));

    // 0) weight convert+transpose to bf16 [N,K]
    wconv_t<<<dim3(3 * DIM / 64, DIM / 64), 256, 0, stream>>>(qkv_w, wT_qkv, DIM, 3 * DIM);
    wconv_t<<<dim3(DIM / 64, DIM / 64), 256, 0, stream>>>(proj_w, wT_proj, DIM, DIM);
    wconv_t<<<dim3(HIDDEN / 64, DIM / 64), 256, 0, stream>>>(fc1_w, wT_fc1, DIM, HIDDEN);
    wconv_t<<<dim3(DIM / 64, HIDDEN / 64), 256, 0, stream>>>(fc2_w, wT_fc2, HIDDEN, DIM);

    // 1) h1 = LN1(x) -> bf16
    ln_kernel<<<ROWS, 256, 0, stream>>>(x, ln1_g, ln1_b, lnout);
    // 2) qkv = h1 @ qkv_w + qkv_b -> bf16   [4096 x 3072]  (grid: m fastest)
    mfma_gemm<<<dim3(ROWS / 128, 3 * DIM / 128), 256, 0, stream>>>(
        lnout, wT_qkv, qkv_b, nullptr, bigbuf, ROWS, 3 * DIM, DIM, 0);
    // 2b) Vt = transpose(V)
    vtrans_kernel<<<dim3(SEQ / 64, BATCH * HEADS), 256, 0, stream>>>(bigbuf, Vt);
    // 3) o = mfma flash attention -> bf16
    fattn_mfma<<<dim3(SEQ / 128, BATCH * HEADS), 256, 0, stream>>>(bigbuf, Vt, attnout);
    // 4) x1 = x + o @ proj_w + proj_b -> d_out (fp32)
    mfma_gemm<<<dim3(ROWS / 128, DIM / 128), 256, 0, stream>>>(
        attnout, wT_proj, proj_b, x, out, ROWS, DIM, DIM, 2);
    // 5) h2 = LN2(x1) -> bf16
    ln_kernel<<<ROWS, 256, 0, stream>>>(out, ln2_g, ln2_b, lnout);
    // 6) g = gelu(h2 @ fc1_w + fc1_b) -> bf16  [4096 x 4096]
    mfma_gemm<<<dim3(ROWS / 128, HIDDEN / 128), 256, 0, stream>>>(
        lnout, wT_fc1, fc1_b, nullptr, bigbuf, ROWS, HIDDEN, DIM, 1);
    // 7) out = x1 + g @ fc2_w + fc2_b -> d_out (fp32)
    mfma_gemm<<<dim3(ROWS / 128, DIM / 128), 256, 0, stream>>>(
        bigbuf, wT_fc2, fc2_b, out, out, ROWS, DIM, HIDDEN, 2);
}

// Round 6
// 485.486 us; speedup vs baseline: 11.5303x; 1.0791x over previous
//
#include <hip/hip_runtime.h>
#include <math.h>

#define DIM    1024
#define HEADS  16
#define HDIM   64
#define HIDDEN 4096
#define BATCH  4
#define SEQ    1024
#define ROWS   (BATCH * SEQ)   // 4096

typedef short s16x8 __attribute__((ext_vector_type(8)));
typedef float f32x4 __attribute__((ext_vector_type(4)));

// ---- bf16 helpers ----
__device__ __forceinline__ float blo(unsigned int u) {
    union { unsigned int i; float f; } x; x.i = u << 16; return x.f;
}
__device__ __forceinline__ float bhi(unsigned int u) {
    union { unsigned int i; float f; } x; x.i = u & 0xffff0000u; return x.f;
}
__device__ __forceinline__ unsigned short f2b(float f) {   // round-to-nearest-even
    union { float f; unsigned int i; } x; x.f = f;
    unsigned int r = x.i + 0x7fffu + ((x.i >> 16) & 1u);
    return (unsigned short)(r >> 16);
}

// ---- async global->LDS, 16B/lane (per-lane global addr; wave-uniform LDS base) ----
__device__ __forceinline__ void gload_lds16(const void* g, void* l) {
    __builtin_amdgcn_global_load_lds(
        (const __attribute__((address_space(1))) unsigned int*)g,
        (__attribute__((address_space(3))) unsigned int*)l, 16, 0, 0);
}

// ---------------- LayerNorm: one block per row; fp32 in -> bf16 out ----------------
__global__ __launch_bounds__(256) void ln_kernel(const float* __restrict__ x,
                                                 const float* __restrict__ g,
                                                 const float* __restrict__ b,
                                                 unsigned short* __restrict__ out) {
    int row = blockIdx.x;
    const float* xr = x + (size_t)row * DIM;
    unsigned short* orow = out + (size_t)row * DIM;
    int t = threadIdx.x;
    float4 v = *((const float4*)(xr + t * 4));
    float s  = v.x + v.y + v.z + v.w;
    float ss = v.x * v.x + v.y * v.y + v.z * v.z + v.w * v.w;
    __shared__ float red1[256], red2[256];
    red1[t] = s; red2[t] = ss;
    __syncthreads();
    for (int off = 128; off > 0; off >>= 1) {
        if (t < off) { red1[t] += red1[t + off]; red2[t] += red2[t + off]; }
        __syncthreads();
    }
    float mu   = red1[0] * (1.0f / DIM);
    float var  = red2[0] * (1.0f / DIM) - mu * mu;
    float rstd = rsqrtf(var + 1e-5f);
    float4 gv = *((const float4*)(g + t * 4));
    float4 bv = *((const float4*)(b + t * 4));
    ushort4 o;
    o.x = f2b((v.x - mu) * rstd * gv.x + bv.x);
    o.y = f2b((v.y - mu) * rstd * gv.y + bv.y);
    o.z = f2b((v.z - mu) * rstd * gv.z + bv.z);
    o.w = f2b((v.w - mu) * rstd * gv.w + bv.w);
    *((ushort4*)(orow + t * 4)) = o;
}

// ------------- Weight convert+transpose: W fp32 [K,N] -> Wt bf16 [N,K] -------------
__global__ __launch_bounds__(256) void wconv_t(const float* __restrict__ W,
                                               unsigned short* __restrict__ Wt,
                                               int K, int N) {
    __shared__ unsigned short T[64][68];
    int t = threadIdx.x;
    int n0 = blockIdx.x * 64, k0 = blockIdx.y * 64;
    int cr = t >> 4;
    int cc = (t & 15) * 4;
    #pragma unroll
    for (int r = 0; r < 4; ++r) {
        int kk = cr + 16 * r;
        float4 v = *((const float4*)(W + (size_t)(k0 + kk) * N + n0 + cc));
        T[cc + 0][kk] = f2b(v.x);
        T[cc + 1][kk] = f2b(v.y);
        T[cc + 2][kk] = f2b(v.z);
        T[cc + 3][kk] = f2b(v.w);
    }
    __syncthreads();
    #pragma unroll
    for (int r = 0; r < 4; ++r) {
        int nn = cr + 16 * r;
        *((ushort4*)(Wt + (size_t)(n0 + nn) * K + k0 + cc)) = *((ushort4*)&T[nn][cc]);
    }
}

// ---------------- MFMA GEMM: C = A[M,K] @ Bt[N,K]^T + bias ----------------
// fuse: 0 = bias, bf16 out; 1 = bias+GELU, bf16 out; 2 = bias+residual(fp32), fp32 out;
//       3 = split-K partial, NO bias, bf16 -> partial buffer p{blockIdx.z}
// 128x128 tile, BK=64, single-buffered 32KB LDS (5 blocks/CU cap -> co-residency
// is what hides the ~4400cyc per-iter wall). Grid: blockIdx.x = m (L2 A-reuse),
// blockIdx.z = K-split index over Ksplit-sized ranges.
__global__ __launch_bounds__(256) void mfma_gemm(const unsigned short* __restrict__ A,
                                                 const unsigned short* __restrict__ Bt,
                                                 const float* __restrict__ bias,
                                                 const float* __restrict__ add,
                                                 void* __restrict__ Cout,
                                                 unsigned short* __restrict__ p0,
                                                 unsigned short* __restrict__ p1,
                                                 unsigned short* __restrict__ p2,
                                                 unsigned short* __restrict__ p3,
                                                 int M, int N, int K, int Ksplit, int fuse) {
    __shared__ __align__(16) short Asm[8192];   // 16 KB
    __shared__ __align__(16) short Bsm[8192];

    const int tid  = threadIdx.x;
    const int lane = tid & 63;
    const int wave = tid >> 6;
    const int wy = wave >> 1, wx = wave & 1;
    const int lr = lane & 15;
    const int lq = lane >> 4;
    const int m0 = blockIdx.x * 128, n0 = blockIdx.y * 128;
    const int kbase = blockIdx.z * Ksplit;

    f32x4 acc[4][4];
    #pragma unroll
    for (int i = 0; i < 4; ++i)
        #pragma unroll
        for (int j = 0; j < 4; ++j)
            acc[i][j] = (f32x4){0.f, 0.f, 0.f, 0.f};

    const unsigned short* ag[4]; const unsigned short* bg[4];
    short* al[4]; short* bl[4];
    #pragma unroll
    for (int j = 0; j < 4; ++j) {
        int cid = wave * 4 + j;
        int rb  = (cid >> 1) * 16 + lr;
        int kk  = (cid & 1) * 32 + lq * 8;
        ag[j] = A  + (size_t)(m0 + rb) * K + kbase + kk;
        bg[j] = Bt + (size_t)(n0 + rb) * K + kbase + kk;
        al[j] = &Asm[cid * 512];
        bl[j] = &Bsm[cid * 512];
    }

    for (int k0 = 0; k0 < Ksplit; k0 += 64) {
        #pragma unroll
        for (int j = 0; j < 4; ++j) {
            gload_lds16(ag[j], al[j]);
            gload_lds16(bg[j], bl[j]);
            ag[j] += 64; bg[j] += 64;
        }
        __syncthreads();
        #pragma unroll
        for (int kc = 0; kc < 2; ++kc) {
            s16x8 af[4], bf[4];
            #pragma unroll
            for (int i = 0; i < 4; ++i)
                af[i] = *((const s16x8*)&Asm[((wy * 4 + i) * 2 + kc) * 512 + lane * 8]);
            #pragma unroll
            for (int j = 0; j < 4; ++j)
                bf[j] = *((const s16x8*)&Bsm[((wx * 4 + j) * 2 + kc) * 512 + lane * 8]);
            #pragma unroll
            for (int i = 0; i < 4; ++i)
                #pragma unroll
                for (int j = 0; j < 4; ++j)
                    acc[i][j] = __builtin_amdgcn_mfma_f32_16x16x32_bf16(af[i], bf[j], acc[i][j], 0, 0, 0);
        }
        __syncthreads();
    }

    unsigned short* P = nullptr;
    if (fuse == 3) {
        int z = blockIdx.z;
        P = (z == 0) ? p0 : (z == 1) ? p1 : (z == 2) ? p2 : p3;
    }

    #pragma unroll
    for (int j = 0; j < 4; ++j) {
        int col = n0 + wx * 64 + j * 16 + lr;
        float bi = (fuse == 3) ? 0.f : bias[col];
        #pragma unroll
        for (int i = 0; i < 4; ++i) {
            int row0 = m0 + wy * 64 + i * 16 + lq * 4;
            #pragma unroll
            for (int r = 0; r < 4; ++r) {
                float val = acc[i][j][r] + bi;
                size_t idx = (size_t)(row0 + r) * N + col;
                if (fuse == 3) {
                    P[idx] = f2b(val);
                } else if (fuse == 2) {
                    ((float*)Cout)[idx] = val + add[idx];
                } else {
                    if (fuse == 1)
                        val = 0.5f * val * (1.0f + erff(val * 0.70710678f));
                    ((unsigned short*)Cout)[idx] = f2b(val);
                }
            }
        }
    }
}

// ---------- Split-K reduce: out = x + bias + sum_s partial_s   (N = DIM cols) ----------
__global__ __launch_bounds__(256) void reduce_kernel(const unsigned short* __restrict__ p0,
                                                     const unsigned short* __restrict__ p1,
                                                     const unsigned short* __restrict__ p2,
                                                     const unsigned short* __restrict__ p3,
                                                     int S,
                                                     const float* __restrict__ x,
                                                     const float* __restrict__ bias,
                                                     float* __restrict__ out) {
    int i = (blockIdx.x * 256 + threadIdx.x) * 8;
    int col = i & (DIM - 1);
    float4 b0 = *((const float4*)(bias + col));
    float4 b1 = *((const float4*)(bias + col + 4));
    float4 x0 = *((const float4*)(x + i));
    float4 x1 = *((const float4*)(x + i + 4));
    float a[8] = {x0.x + b0.x, x0.y + b0.y, x0.z + b0.z, x0.w + b0.w,
                  x1.x + b1.x, x1.y + b1.y, x1.z + b1.z, x1.w + b1.w};
    const unsigned short* ps[4] = {p0, p1, p2, p3};
    for (int s = 0; s < S; ++s) {
        uint4 w = *((const uint4*)(ps[s] + i));
        a[0] += blo(w.x); a[1] += bhi(w.x);
        a[2] += blo(w.y); a[3] += bhi(w.y);
        a[4] += blo(w.z); a[5] += bhi(w.z);
        a[6] += blo(w.w); a[7] += bhi(w.w);
    }
    *((float4*)(out + i))     = make_float4(a[0], a[1], a[2], a[3]);
    *((float4*)(out + i + 4)) = make_float4(a[4], a[5], a[6], a[7]);
}

// ------------- V transpose: qkv [B,N,3,H,64] -> Vt [BH][64 d][SEQ] (bf16) -------------
__global__ __launch_bounds__(256) void vtrans_kernel(const unsigned short* __restrict__ qkv,
                                                     unsigned short* __restrict__ Vt) {
    __shared__ unsigned short T[64][72];
    int bh = blockIdx.y; int b = bh >> 4, h = bh & 15;
    int t0 = blockIdx.x * 64;
    int tid = threadIdx.x;
    {
        int i = tid >> 2;
        int c = (tid & 3) * 16;
        const unsigned short* src = qkv + ((size_t)(b * SEQ + t0 + i)) * (3 * DIM) + 2 * DIM + h * 64 + c;
        *((uint4*)&T[i][c])     = *((const uint4*)src);
        *((uint4*)&T[i][c + 8]) = *((const uint4*)(src + 8));
    }
    __syncthreads();
    {
        int d  = tid >> 2;
        int kg = (tid & 3) * 16;
        unsigned short pk[16];
        #pragma unroll
        for (int j = 0; j < 16; ++j) pk[j] = T[kg + j][d];
        unsigned short* dst = Vt + ((size_t)bh * 64 + d) * SEQ + t0 + kg;
        *((uint4*)dst)       = *((uint4*)&pk[0]);
        *((uint4*)(dst + 8)) = *((uint4*)&pk[8]);
    }
}

// ------------- MFMA flash attention: block = (bh) x 128-q tile, 4 waves -------------
__global__ __launch_bounds__(256) void fattn_mfma(const unsigned short* __restrict__ qkv,
                                                  const unsigned short* __restrict__ Vt,
                                                  unsigned short* __restrict__ out) {
    __shared__ __align__(16) short Qs[8192];
    __shared__ __align__(16) short Ks[4096];
    __shared__ __align__(16) short Vs[4096];
    __shared__ __align__(16) short Ps[128 * 72];

    const int tid = threadIdx.x, lane = tid & 63, wave = tid >> 6;
    const int lr = lane & 15, lq = lane >> 4;
    const int bh = blockIdx.y, b = bh >> 4, h = bh & 15;
    const int q0 = blockIdx.x * 128;

    #pragma unroll
    for (int j = 0; j < 4; ++j) {
        int cid = wave * 4 + j;
        const unsigned short* g = qkv + ((size_t)(b * SEQ + q0 + 16 * (cid >> 1) + lr)) * (3 * DIM)
                                  + h * 64 + (cid & 1) * 32 + lq * 8;
        gload_lds16(g, &Qs[cid * 512]);
    }

    const unsigned short* kg_[2]; const unsigned short* vg_[2];
    short *kl_[2], *vl_[2];
    #pragma unroll
    for (int j = 0; j < 2; ++j) {
        int cid = wave * 2 + j;
        kg_[j] = qkv + ((size_t)(b * SEQ + 16 * (cid >> 1) + lr)) * (3 * DIM)
                 + DIM + h * 64 + (cid & 1) * 32 + lq * 8;
        vg_[j] = Vt + ((size_t)(bh * 64 + 16 * (cid >> 1) + lr)) * SEQ + (cid & 1) * 32 + lq * 8;
        kl_[j] = &Ks[cid * 512];
        vl_[j] = &Vs[cid * 512];
    }

    f32x4 osum[2][4];
    float mrow[2][4], lrow[2][4];
    #pragma unroll
    for (int i = 0; i < 2; ++i)
        #pragma unroll
        for (int d = 0; d < 4; ++d) {
            osum[i][d] = (f32x4){0.f, 0.f, 0.f, 0.f};
            mrow[i][d] = -1e30f; lrow[i][d] = 0.f;
        }

    for (int k0 = 0; k0 < SEQ; k0 += 64) {
        #pragma unroll
        for (int j = 0; j < 2; ++j) {
            gload_lds16(kg_[j], kl_[j]);
            gload_lds16(vg_[j], vl_[j]);
            kg_[j] += 64 * 3 * DIM;
            vg_[j] += 64;
        }
        __syncthreads();

        f32x4 s[2][4];
        #pragma unroll
        for (int i = 0; i < 2; ++i)
            #pragma unroll
            for (int jb = 0; jb < 4; ++jb)
                s[i][jb] = (f32x4){0.f, 0.f, 0.f, 0.f};
        #pragma unroll
        for (int kc = 0; kc < 2; ++kc) {
            s16x8 aq0 = *((const s16x8*)&Qs[(wave * 4 + 0 + kc) * 512 + lane * 8]);
            s16x8 aq1 = *((const s16x8*)&Qs[(wave * 4 + 2 + kc) * 512 + lane * 8]);
            #pragma unroll
            for (int jb = 0; jb < 4; ++jb) {
                s16x8 bk = *((const s16x8*)&Ks[(jb * 2 + kc) * 512 + lane * 8]);
                s[0][jb] = __builtin_amdgcn_mfma_f32_16x16x32_bf16(aq0, bk, s[0][jb], 0, 0, 0);
                s[1][jb] = __builtin_amdgcn_mfma_f32_16x16x32_bf16(aq1, bk, s[1][jb], 0, 0, 0);
            }
        }

        #pragma unroll
        for (int i = 0; i < 2; ++i) {
            #pragma unroll
            for (int r = 0; r < 4; ++r) {
                float mx = fmaxf(fmaxf(s[i][0][r], s[i][1][r]), fmaxf(s[i][2][r], s[i][3][r]));
                mx = fmaxf(mx, __shfl_xor(mx, 1, 64));
                mx = fmaxf(mx, __shfl_xor(mx, 2, 64));
                mx = fmaxf(mx, __shfl_xor(mx, 4, 64));
                mx = fmaxf(mx, __shfl_xor(mx, 8, 64));
                float mn = fmaxf(mrow[i][r], mx);
                float al = __expf(0.125f * (mrow[i][r] - mn));
                mrow[i][r] = mn;
                float rs = 0.f;
                int prow = (wave * 2 + i) * 16 + lq * 4 + r;
                #pragma unroll
                for (int jb = 0; jb < 4; ++jb) {
                    float p = __expf(0.125f * (s[i][jb][r] - mn));
                    rs += p;
                    Ps[prow * 72 + jb * 16 + lr] = (short)f2b(p);
                }
                rs += __shfl_xor(rs, 1, 64);
                rs += __shfl_xor(rs, 2, 64);
                rs += __shfl_xor(rs, 4, 64);
                rs += __shfl_xor(rs, 8, 64);
                lrow[i][r] = lrow[i][r] * al + rs;
                #pragma unroll
                for (int db = 0; db < 4; ++db) osum[i][db][r] *= al;
            }
        }

        #pragma unroll
        for (int kc = 0; kc < 2; ++kc) {
            s16x8 ap0 = *((const s16x8*)&Ps[((wave * 2 + 0) * 16 + lr) * 72 + kc * 32 + lq * 8]);
            s16x8 ap1 = *((const s16x8*)&Ps[((wave * 2 + 1) * 16 + lr) * 72 + kc * 32 + lq * 8]);
            #pragma unroll
            for (int db = 0; db < 4; ++db) {
                s16x8 bv = *((const s16x8*)&Vs[(db * 2 + kc) * 512 + lane * 8]);
                osum[0][db] = __builtin_amdgcn_mfma_f32_16x16x32_bf16(ap0, bv, osum[0][db], 0, 0, 0);
                osum[1][db] = __builtin_amdgcn_mfma_f32_16x16x32_bf16(ap1, bv, osum[1][db], 0, 0, 0);
            }
        }
        __syncthreads();
    }

    #pragma unroll
    for (int i = 0; i < 2; ++i) {
        int qrow = q0 + (wave * 2 + i) * 16 + lq * 4;
        #pragma unroll
        for (int r = 0; r < 4; ++r) {
            float inv = 1.0f / lrow[i][r];
            size_t rowoff = ((size_t)(b * SEQ + qrow + r)) * DIM + h * 64;
            #pragma unroll
            for (int db = 0; db < 4; ++db)
                out[rowoff + db * 16 + lr] = f2b(osum[i][db][r] * inv);
        }
    }
}

extern "C" void kernel_launch(void* const* d_in, const int* in_sizes, int n_in,
                              void* d_out, int out_size, void* d_ws, size_t ws_size,
                              hipStream_t stream) {
    const float* x      = (const float*)d_in[0];
    const float* ln1_g  = (const float*)d_in[1];
    const float* ln1_b  = (const float*)d_in[2];
    const float* ln2_g  = (const float*)d_in[3];
    const float* ln2_b  = (const float*)d_in[4];
    const float* qkv_w  = (const float*)d_in[5];
    const float* qkv_b  = (const float*)d_in[6];
    const float* proj_w = (const float*)d_in[7];
    const float* proj_b = (const float*)d_in[8];
    const float* fc1_w  = (const float*)d_in[9];
    const float* fc1_b  = (const float*)d_in[10];
    const float* fc2_w  = (const float*)d_in[11];
    const float* fc2_b  = (const float*)d_in[12];
    float* out = (float*)d_out;

    // workspace layout (MiB), 72 total. Liveness-packed:
    //  [0,8)   wT_fc2            (alive until FC2)
    //  [8,14)  wT_qkv            (dead after QKV)     -> FC2 partial P3 region tail
    //  [14,16) wT_proj           (dead after proj)
    //  [16,40) qkv bf16 24MiB    (dead after fattn)   -> proj partials / gelu
    //  [40,48) Vt                (dead after fattn)   -> gelu tail
    //  [48,56) attnout           (dead after proj)    -> FC2 partial P0
    //  [56,64) lnout             (dead after FC1)     -> FC2 partial P1
    //  [64,72) wT_fc1            (dead after FC1)     -> FC2 partial P2
    char* ws = (char*)d_ws;
    unsigned short* wT_fc2  = (unsigned short*)(ws);
    unsigned short* wT_qkv  = (unsigned short*)(ws + (8u  << 20));
    unsigned short* wT_proj = (unsigned short*)(ws + (14u << 20));
    unsigned short* qkvbuf  = (unsigned short*)(ws + (16u << 20));
    unsigned short* Vt      = (unsigned short*)(ws + (40u << 20));
    unsigned short* attnout = (unsigned short*)(ws + (48u << 20));
    unsigned short* lnout   = (unsigned short*)(ws + (56u << 20));
    unsigned short* wT_fc1  = (unsigned short*)(ws + (64u << 20));
    unsigned short* gelu    = (unsigned short*)(ws + (16u << 20));   // 32MiB [16,48)
    // proj split-K partials (S=2) in dead qkv region:
    unsigned short* pp0 = (unsigned short*)(ws + (16u << 20));
    unsigned short* pp1 = (unsigned short*)(ws + (24u << 20));
    // FC2 split-K partials (S=4) in dead attnout/lnout/wT_fc1/wT_qkv regions:
    unsigned short* fp0 = (unsigned short*)(ws + (48u << 20));
    unsigned short* fp1 = (unsigned short*)(ws + (56u << 20));
    unsigned short* fp2 = (unsigned short*)(ws + (64u << 20));
    unsigned short* fp3 = (unsigned short*)(ws + (8u  << 20));

    // 0) weight convert+transpose to bf16 [N,K]
    wconv_t<<<dim3(3 * DIM / 64, DIM / 64), 256, 0, stream>>>(qkv_w, wT_qkv, DIM, 3 * DIM);
    wconv_t<<<dim3(DIM / 64, DIM / 64), 256, 0, stream>>>(proj_w, wT_proj, DIM, DIM);
    wconv_t<<<dim3(HIDDEN / 64, DIM / 64), 256, 0, stream>>>(fc1_w, wT_fc1, DIM, HIDDEN);
    wconv_t<<<dim3(DIM / 64, HIDDEN / 64), 256, 0, stream>>>(fc2_w, wT_fc2, HIDDEN, DIM);

    // 1) h1 = LN1(x) -> bf16
    ln_kernel<<<ROWS, 256, 0, stream>>>(x, ln1_g, ln1_b, lnout);
    // 2) qkv = h1 @ qkv_w + qkv_b -> bf16   [4096 x 3072]
    mfma_gemm<<<dim3(ROWS / 128, 3 * DIM / 128, 1), 256, 0, stream>>>(
        lnout, wT_qkv, qkv_b, nullptr, qkvbuf, nullptr, nullptr, nullptr, nullptr,
        ROWS, 3 * DIM, DIM, DIM, 0);
    // 2b) Vt = transpose(V)
    vtrans_kernel<<<dim3(SEQ / 64, BATCH * HEADS), 256, 0, stream>>>(qkvbuf, Vt);
    // 3) o = mfma flash attention -> bf16
    fattn_mfma<<<dim3(SEQ / 128, BATCH * HEADS), 256, 0, stream>>>(qkvbuf, Vt, attnout);
    // 4) proj split-K (S=2): partials = o @ proj_w
    mfma_gemm<<<dim3(ROWS / 128, DIM / 128, 2), 256, 0, stream>>>(
        attnout, wT_proj, proj_b, nullptr, nullptr, pp0, pp1, nullptr, nullptr,
        ROWS, DIM, DIM, DIM / 2, 3);
    // 4b) x1 = x + sum(partials) + proj_b -> d_out (fp32)
    reduce_kernel<<<ROWS * DIM / 2048, 256, 0, stream>>>(
        pp0, pp1, nullptr, nullptr, 2, x, proj_b, out);
    // 5) h2 = LN2(x1) -> bf16
    ln_kernel<<<ROWS, 256, 0, stream>>>(out, ln2_g, ln2_b, lnout);
    // 6) g = gelu(h2 @ fc1_w + fc1_b) -> bf16  [4096 x 4096]
    mfma_gemm<<<dim3(ROWS / 128, HIDDEN / 128, 1), 256, 0, stream>>>(
        lnout, wT_fc1, fc1_b, nullptr, gelu, nullptr, nullptr, nullptr, nullptr,
        ROWS, HIDDEN, DIM, DIM, 1);
    // 7) FC2 split-K (S=4): partials = g @ fc2_w
    mfma_gemm<<<dim3(ROWS / 128, DIM / 128, 4), 256, 0, stream>>>(
        gelu, wT_fc2, fc2_b, nullptr, nullptr, fp0, fp1, fp2, fp3,
        ROWS, DIM, HIDDEN, HIDDEN / 4, 3);
    // 7b) out = x1 + sum(partials) + fc2_b -> d_out (fp32, in-place residual)
    reduce_kernel<<<ROWS * DIM / 2048, 256, 0, stream>>>(
        fp0, fp1, fp2, fp3, 4, out, fc2_b, out);
}